// Round 1
// baseline (328.726 us; speedup 1.0000x reference)
//
#include <hip/hip_runtime.h>

// GQA fused pipeline, bf16 MFMA, gfx950.
// cvt(fp32->bf16) -> fused QKV GEMM (m97 single-buffer structure) ->
// flash attention (8-wave blocks, tile-per-wave-group, in-register P) ->
// Wo GEMM (m97 single-buffer structure).

#define B_   2
#define S_   2048
#define DIN  2048
#define NH   32
#define NKV  8
#define HD   64
#define DOUT 2048
#define NQKV 3072

#define QSCALE 0.18033688f  // 0.125 * log2(e), folded into Q

typedef short bf16x8 __attribute__((ext_vector_type(8)));
typedef short bf16x4 __attribute__((ext_vector_type(4)));
typedef float f32x4  __attribute__((ext_vector_type(4)));

__device__ __forceinline__ unsigned short f2bf(float f) {
  unsigned int u = __float_as_uint(f);
  u += 0x7fff + ((u >> 16) & 1);  // RNE
  return (unsigned short)(u >> 16);
}

__device__ __forceinline__ f32x4 mfma16(bf16x4 a, bf16x4 b, f32x4 c) {
#if __has_builtin(__builtin_amdgcn_mfma_f32_16x16x16bf16_1k)
  return __builtin_amdgcn_mfma_f32_16x16x16bf16_1k(a, b, c, 0, 0, 0);
#else
  asm volatile("v_mfma_f32_16x16x16_bf16 %0, %1, %2, %0" : "+v"(c) : "v"(a), "v"(b));
  return c;
#endif
}

__device__ __forceinline__ void gld_lds16(const void* gptr, void* lptr) {
  __builtin_amdgcn_global_load_lds(
      (const __attribute__((address_space(1))) unsigned int*)gptr,
      (__attribute__((address_space(3))) unsigned int*)lptr,
      16, 0, 0);
}

// single conversion kernel for all 5 tensors (boundaries multiples of 256).
__global__ __launch_bounds__(256) void cvt_all(
    const float* __restrict__ x,  const float* __restrict__ Wq,
    const float* __restrict__ Wk, const float* __restrict__ Wv,
    const float* __restrict__ Wo,
    unsigned short* __restrict__ xbf, unsigned short* __restrict__ wqkv,
    unsigned short* __restrict__ wobf) {
  int i = blockIdx.x * blockDim.x + threadIdx.x;
  const float* src; unsigned short* dst; int off;
  if (i < 2097152)      { src = x;  dst = xbf;                  off = i; }
  else if (i < 3145728) { src = Wq; dst = wqkv;                 off = i - 2097152; }
  else if (i < 3407872) { src = Wk; dst = wqkv + 2048 * 2048;   off = i - 3145728; }
  else if (i < 3670016) { src = Wv; dst = wqkv + 2560 * 2048;   off = i - 3407872; }
  else                  { src = Wo; dst = wobf;                 off = i - 3670016; }
  float4 f = ((const float4*)src)[off];
  ushort4 o;
  o.x = f2bf(f.x); o.y = f2bf(f.y); o.z = f2bf(f.z); o.w = f2bf(f.w);
  ((ushort4*)dst)[off] = o;
}

// C = A @ B^T. 128x128 tile, BK=64, 4 waves 2x2, 4x4 16x16x32 MFMA per wave.
// m97 single-buffer structure: 32 KiB LDS total -> ~3 blocks/CU resident
// (VGPR-limited), wave-level overlap across blocks hides the barrier drain.
// stage -> barrier -> compute -> barrier, 2 barriers per K-step.
template <int MODE>
__global__ __launch_bounds__(256) void gemm_bt(
    const unsigned short* __restrict__ A,
    const unsigned short* __restrict__ Bm,
    int K,
    unsigned short* __restrict__ qbf,
    unsigned short* __restrict__ kbf,
    unsigned short* __restrict__ vtbf,
    float* __restrict__ kout,
    float* __restrict__ vout,
    float* __restrict__ cout) {
  __shared__ unsigned short As[8192];
  __shared__ unsigned short Bs[8192];
  const int tid  = threadIdx.x;
  const int lane = tid & 63;
  const int wave = tid >> 6;
  const int wm   = wave & 1;
  const int wn   = wave >> 1;
  const int quad = lane >> 4;
  const int r16  = lane & 15;
  const int crow = lane >> 3;
  const int ccol = (lane & 7) * 8;

  const int aRowBase = blockIdx.y * 128;
  const int bRowBase = blockIdx.x * 128;

  f32x4 zero = {0.f, 0.f, 0.f, 0.f};
  f32x4 acc[4][4];
#pragma unroll
  for (int i = 0; i < 4; ++i)
#pragma unroll
    for (int j = 0; j < 4; ++j) acc[i][j] = zero;

  auto stage = [&](int k0) {
#pragma unroll
    for (int i = 0; i < 4; ++i) {
      const int seg = wave * 4 + i;
      const int row = seg * 8 + crow;
      gld_lds16(A  + (size_t)(aRowBase + row) * K + k0 + ccol, &As[seg * 512]);
      gld_lds16(Bm + (size_t)(bRowBase + row) * K + k0 + ccol, &Bs[seg * 512]);
    }
  };

  for (int k0 = 0; k0 < K; k0 += 64) {
    stage(k0);
    __syncthreads();  // loads landed in LDS (vmcnt drained at barrier)
#pragma unroll
    for (int kk = 0; kk < 2; ++kk) {
      bf16x8 af[4], bfr[4];
#pragma unroll
      for (int mt = 0; mt < 4; ++mt)
        af[mt] = *(const bf16x8*)(&As[(wm * 64 + mt * 16 + r16) * 64 + kk * 32 + quad * 8]);
#pragma unroll
      for (int nt = 0; nt < 4; ++nt)
        bfr[nt] = *(const bf16x8*)(&Bs[(wn * 64 + nt * 16 + r16) * 64 + kk * 32 + quad * 8]);
#pragma unroll
      for (int mt = 0; mt < 4; ++mt)
#pragma unroll
        for (int nt = 0; nt < 4; ++nt)
          acc[mt][nt] = __builtin_amdgcn_mfma_f32_16x16x32_bf16(af[mt], bfr[nt], acc[mt][nt], 0, 0, 0);
    }
    __syncthreads();  // all reads done before next stage overwrites
  }

#pragma unroll
  for (int mt = 0; mt < 4; ++mt) {
#pragma unroll
    for (int nt = 0; nt < 4; ++nt) {
      const int rowb = aRowBase + wm * 64 + mt * 16 + quad * 4;
      const int col  = bRowBase + wn * 64 + nt * 16 + r16;
#pragma unroll
      for (int reg = 0; reg < 4; ++reg) {
        const float v = acc[mt][nt][reg];
        const int m = rowb + reg;
        if (MODE == 1) {
          cout[(size_t)m * DOUT + col] = v;
        } else {
          if (col < 2048) {
            qbf[(size_t)m * DOUT + col] = f2bf(v * QSCALE);
          } else if (col < 2560) {
            const int gg = (col - 2048) >> 6, d = col & 63;
            const int b = m >> 11, s = m & 2047;
            const size_t idx = ((size_t)(b * NKV + gg) * S_ + s) * HD + d;
            kbf[idx]  = f2bf(v);
            kout[idx] = v;
          } else {
            const int gg = (col - 2560) >> 6, d = col & 63;
            const int b = m >> 11, s = m & 2047;
            vtbf[((size_t)(b * NKV + gg) * HD + d) * S_ + s]  = f2bf(v);
            vout[((size_t)(b * NKV + gg) * S_ + s) * HD + d] = v;
          }
        }
      }
    }
  }
}

// Flash attention, causal, m=0 softmax, in-register P (S^T operand-swap).
// 8 waves: group 0 (waves 0-3) = heavy tile (63-pairI), group 1 = light tile
// (pairI); wave = one head. K/V double-buffered via global_load_lds with
// prefetch-before-compute. One wave's work per kt = 1 tile (halved vs R4).
__global__ __launch_bounds__(512, 4) void attn_kernel(
    const unsigned short* __restrict__ Q,   // [B*S][DOUT] bf16 (scaled)
    const unsigned short* __restrict__ Kb,  // [B*NKV][S][HD] bf16
    const unsigned short* __restrict__ VT,  // [B*NKV][HD][S] bf16
    unsigned short* __restrict__ ctx) {     // [B*S][DOUT] bf16
  __shared__ unsigned short Kbuf[2][4096];  // 64 keys x 64 d, XOR-swizzled
  __shared__ unsigned short Vbuf[2][4096];  // 64 d x 64 keys, XOR-swizzled

  const int tid  = threadIdx.x;
  const int lane = tid & 63;
  const int wave = tid >> 6;   // 0..7
  const int grp  = wave >> 2;  // 0 = heavy tile, 1 = light tile
  const int hw   = wave & 3;
  const int quad = lane >> 4;
  const int r16  = lane & 15;
  const int g    = blockIdx.y;
  const int b    = blockIdx.z;
  const int h    = g * 4 + hw;
  const int pairI = blockIdx.x;  // 0..31, heavy-first
  const int q0     = grp ? pairI * 32 : (63 - pairI) * 32;
  const int nT_own = grp ? pairI / 2 + 1 : (63 - pairI) / 2 + 1;
  const int nTa    = (63 - pairI) / 2 + 1;  // block loop bound

  const unsigned short* Kh  = Kb + (size_t)(b * NKV + g) * S_ * HD;
  const unsigned short* VTh = VT + (size_t)(b * NKV + g) * HD * S_;

  const int srow   = lane >> 3;
  const int schunk = (lane & 7) ^ srow;

  // Q fragments (B-operand of S^T MFMA; same layout as A-operand)
  bf16x8 aq[2][2];
#pragma unroll
  for (int mt = 0; mt < 2; ++mt)
#pragma unroll
    for (int kk = 0; kk < 2; ++kk)
      aq[mt][kk] = *(const bf16x8*)(Q + (size_t)(b * S_ + q0 + mt * 16 + r16) * DOUT +
                                    h * HD + kk * 32 + quad * 8);

  bf16x4 ones4;
#pragma unroll
  for (int i = 0; i < 4; ++i) ones4[i] = (short)0x3F80;

  f32x4 zero = {0.f, 0.f, 0.f, 0.f};
  f32x4 o[2][4];  // [mt][dt]; C layout: row=q=quad*4+r, col=d=dt*16+r16
  f32x4 l[2];
#pragma unroll
  for (int mt = 0; mt < 2; ++mt) {
    l[mt] = zero;
#pragma unroll
    for (int dt = 0; dt < 4; ++dt) o[mt][dt] = zero;
  }

  // each wave stages one 8-row segment of K and of V^T (wave-uniform base)
  auto stage = [&](int buf, int kt) {
    const int kbase = kt * 64;
    gld_lds16(Kh + (size_t)(kbase + wave * 8 + srow) * HD + schunk * 8,
              &Kbuf[buf][wave * 512]);
    gld_lds16(VTh + (size_t)(wave * 8 + srow) * S_ + kbase + schunk * 8,
              &Vbuf[buf][wave * 512]);
  };

  stage(0, 0);
  __syncthreads();

  for (int kt = 0; kt < nTa; ++kt) {
    const int buf = kt & 1;
    if (kt + 1 < nTa) stage(buf ^ 1, kt + 1);

    if (kt < nT_own) {
      // K fragments: A-operand of S^T MFMA (m=key=r16 within tile nt)
      bf16x8 bk[4][2];
#pragma unroll
      for (int nt = 0; nt < 4; ++nt)
#pragma unroll
        for (int kk = 0; kk < 2; ++kk) {
          const int seg = nt * 2 + (r16 >> 3), r = r16 & 7;
          const int slot = (kk * 4 + quad) ^ r;
          bk[nt][kk] = *(const bf16x8*)&Kbuf[buf][seg * 512 + r * 64 + slot * 8];
        }

      const bool last = (kt == nT_own - 1);
#pragma unroll
      for (int mt = 0; mt < 2; ++mt) {
        // S^T = K.Q^T
        f32x4 st[4];
#pragma unroll
        for (int nt = 0; nt < 4; ++nt) st[nt] = zero;
#pragma unroll
        for (int kk = 0; kk < 2; ++kk)
#pragma unroll
          for (int nt = 0; nt < 4; ++nt)
            st[nt] = __builtin_amdgcn_mfma_f32_16x16x32_bf16(bk[nt][kk], aq[mt][kk], st[nt], 0, 0, 0);

        // mask + exp2 -> P A-fragments (K=16 layout), truncating bf16 pack
        bf16x4 pf[4];
#pragma unroll
        for (int nt = 0; nt < 4; ++nt) {
#pragma unroll
          for (int r = 0; r < 4; ++r) {
            float s = st[nt][r];
            if (last) {
              const int key = kt * 64 + nt * 16 + quad * 4 + r;
              const int row = q0 + mt * 16 + r16;
              if (key > row) s = -1e38f;
            }
            const float p = __builtin_amdgcn_exp2f(s);
            pf[nt][r] = (short)(__float_as_uint(p) >> 16);
          }
        }
        // row-sums via ones-MFMA, then PV with just-in-time V fragments
#pragma unroll
        for (int nt = 0; nt < 4; ++nt) l[mt] = mfma16(pf[nt], ones4, l[mt]);
#pragma unroll
        for (int dt = 0; dt < 4; ++dt) {
          const int seg = dt * 2 + (r16 >> 3), r = r16 & 7;
#pragma unroll
          for (int nt = 0; nt < 4; ++nt) {
            const int slot = (nt * 2 + (quad >> 1)) ^ r;
            bf16x4 bv = *(const bf16x4*)&Vbuf[buf][seg * 512 + r * 64 + slot * 8 + (quad & 1) * 4];
            o[mt][dt] = mfma16(pf[nt], bv, o[mt][dt]);
          }
        }
      }
    }

    __syncthreads();  // prefetch aged a full compute phase; swap buffers
  }

#pragma unroll
  for (int mt = 0; mt < 2; ++mt) {
    f32x4 rl;
#pragma unroll
    for (int r = 0; r < 4; ++r) rl[r] = __builtin_amdgcn_rcpf(l[mt][r]);
#pragma unroll
    for (int dt = 0; dt < 4; ++dt)
#pragma unroll
      for (int r = 0; r < 4; ++r) {
        const int qq = q0 + mt * 16 + quad * 4 + r;
        ctx[(size_t)(b * S_ + qq) * DOUT + h * HD + dt * 16 + r16] =
            f2bf(o[mt][dt][r] * rl[r]);
      }
  }
}

extern "C" void kernel_launch(void* const* d_in, const int* in_sizes, int n_in,
                              void* d_out, int out_size, void* d_ws, size_t ws_size,
                              hipStream_t stream) {
  const float* x  = (const float*)d_in[0];
  const float* Wq = (const float*)d_in[1];
  const float* Wk = (const float*)d_in[2];
  const float* Wv = (const float*)d_in[3];
  const float* Wo = (const float*)d_in[4];

  float* out  = (float*)d_out;
  float* keys = out + (size_t)B_ * S_ * DOUT;
  float* vals = keys + (size_t)B_ * NKV * S_ * HD;

  unsigned short* xbf  = (unsigned short*)d_ws;
  unsigned short* wqkv = xbf  + (size_t)B_ * S_ * DIN;
  unsigned short* wobf = wqkv + (size_t)NQKV * DIN;
  unsigned short* qbf  = wobf + (size_t)DIN * DOUT;
  unsigned short* kbf  = qbf  + (size_t)B_ * S_ * DOUT;
  unsigned short* vtbf = kbf  + (size_t)B_ * NKV * S_ * HD;
  unsigned short* ctx  = vtbf + (size_t)B_ * NKV * S_ * HD;

  cvt_all<<<dim3(4718592 / 256), dim3(256), 0, stream>>>(x, Wq, Wk, Wv, Wo,
                                                         xbf, wqkv, wobf);

  gemm_bt<0><<<dim3(NQKV / 128, (B_ * S_) / 128), dim3(256), 0, stream>>>(
      xbf, wqkv, DIN, qbf, kbf, vtbf, keys, vals, nullptr);

  attn_kernel<<<dim3(32, NKV, B_), dim3(512), 0, stream>>>(qbf, kbf, vtbf, ctx);

  gemm_bt<1><<<dim3(DOUT / 128, (B_ * S_) / 128), dim3(256), 0, stream>>>(
      ctx, wobf, DOUT, nullptr, nullptr, nullptr, nullptr, nullptr, out);
}

// Round 2
// 320.212 us; speedup vs baseline: 1.0266x; 1.0266x over previous
//
#include <hip/hip_runtime.h>

// GQA fused pipeline, bf16 MFMA, gfx950.
// cvt(fp32->bf16) -> fused QKV GEMM (256-tile 4-phase counted-vmcnt schedule,
// T2 swizzle + T5 setprio) -> flash attention (unchanged) -> Wo GEMM (same
// schedule, 256x128 tile for full-grid coverage).

#define B_   2
#define S_   2048
#define DIN  2048
#define NH   32
#define NKV  8
#define HD   64
#define DOUT 2048
#define NQKV 3072

#define QSCALE 0.18033688f  // 0.125 * log2(e), folded into Q

typedef short bf16x8 __attribute__((ext_vector_type(8)));
typedef short bf16x4 __attribute__((ext_vector_type(4)));
typedef float f32x4  __attribute__((ext_vector_type(4)));

__device__ __forceinline__ unsigned short f2bf(float f) {
  unsigned int u = __float_as_uint(f);
  u += 0x7fff + ((u >> 16) & 1);  // RNE
  return (unsigned short)(u >> 16);
}

__device__ __forceinline__ f32x4 mfma16(bf16x4 a, bf16x4 b, f32x4 c) {
#if __has_builtin(__builtin_amdgcn_mfma_f32_16x16x16bf16_1k)
  return __builtin_amdgcn_mfma_f32_16x16x16bf16_1k(a, b, c, 0, 0, 0);
#else
  asm volatile("v_mfma_f32_16x16x16_bf16 %0, %1, %2, %0" : "+v"(c) : "v"(a), "v"(b));
  return c;
#endif
}

__device__ __forceinline__ void gld_lds16(const void* gptr, void* lptr) {
  __builtin_amdgcn_global_load_lds(
      (const __attribute__((address_space(1))) unsigned int*)gptr,
      (__attribute__((address_space(3))) unsigned int*)lptr,
      16, 0, 0);
}

// raw barrier (no implicit vmcnt drain) + compiler-level memory fence so LDS
// reads/stage issues cannot be moved across phase boundaries.
#define BAR()                              \
  do {                                     \
    asm volatile("" ::: "memory");         \
    __builtin_amdgcn_s_barrier();          \
    asm volatile("" ::: "memory");         \
  } while (0)

#define VMCNT(n) asm volatile("s_waitcnt vmcnt(" #n ")" ::: "memory")

// single conversion kernel for all 5 tensors (boundaries multiples of 256).
__global__ __launch_bounds__(256) void cvt_all(
    const float* __restrict__ x,  const float* __restrict__ Wq,
    const float* __restrict__ Wk, const float* __restrict__ Wv,
    const float* __restrict__ Wo,
    unsigned short* __restrict__ xbf, unsigned short* __restrict__ wqkv,
    unsigned short* __restrict__ wobf) {
  int i = blockIdx.x * blockDim.x + threadIdx.x;
  const float* src; unsigned short* dst; int off;
  if (i < 2097152)      { src = x;  dst = xbf;                  off = i; }
  else if (i < 3145728) { src = Wq; dst = wqkv;                 off = i - 2097152; }
  else if (i < 3407872) { src = Wk; dst = wqkv + 2048 * 2048;   off = i - 3145728; }
  else if (i < 3670016) { src = Wv; dst = wqkv + 2560 * 2048;   off = i - 3407872; }
  else                  { src = Wo; dst = wobf;                 off = i - 3670016; }
  float4 f = ((const float4*)src)[off];
  ushort4 o;
  o.x = f2bf(f.x); o.y = f2bf(f.y); o.z = f2bf(f.z); o.w = f2bf(f.w);
  ((ushort4*)dst)[off] = o;
}

// C = A @ B^T, 256x(BN) tile, BK=64, 8 waves (2 M x 4 N), 512 threads.
// 4 phases per K-tile (quadrants (0,0),(0,1),(1,0),(1,1)); per phase:
// {ds_read new frags; issue 1 half-stage; barrier; setprio(1) MFMA x (8*NR)
// setprio(0); [vmcnt(W) at P1/P4]; barrier}. Counted vmcnt, never 0 in loop.
// LDS XOR swizzle (slot ^= row&7) applied on BOTH sides: pre-swizzled global
// source for global_load_lds (linear LDS dest) + swizzled ds_read address.
#define MMA_PHASE(MH, NH, BF)                                                   \
  do {                                                                          \
    __builtin_amdgcn_s_setprio(1);                                              \
    _Pragma("unroll")                                                           \
    for (int mr = 0; mr < 4; ++mr)                                              \
      _Pragma("unroll")                                                         \
      for (int nr = 0; nr < NR; ++nr)                                           \
        _Pragma("unroll")                                                       \
        for (int kk = 0; kk < 2; ++kk)                                          \
          acc[(MH) * 4 + mr][(NH) * NR + nr] =                                  \
              __builtin_amdgcn_mfma_f32_16x16x32_bf16(                          \
                  af[mr][kk], BF[nr][kk], acc[(MH) * 4 + mr][(NH) * NR + nr],   \
                  0, 0, 0);                                                     \
    __builtin_amdgcn_s_setprio(0);                                              \
  } while (0)

template <int MODE, int BN, int NTN>
__global__ __launch_bounds__(512, 2) void gemm8p(
    const unsigned short* __restrict__ A,
    const unsigned short* __restrict__ Bm,
    int K,
    unsigned short* __restrict__ qbf,
    unsigned short* __restrict__ kbf,
    unsigned short* __restrict__ vtbf,
    float* __restrict__ kout,
    float* __restrict__ vout,
    float* __restrict__ cout) {
  constexpr int NR = BN / 128;        // B fragments per quadrant (2 or 1)
  constexpr int BHROW = BN / 2;       // rows per B half-tile
  __shared__ unsigned short As[2][256 * 64];
  __shared__ unsigned short Bs[2][BN * 64];

  const int tid  = threadIdx.x;
  const int lane = tid & 63;
  const int wave = tid >> 6;  // 0..7
  const int wm   = wave >> 2; // 0..1
  const int wn   = wave & 3;  // 0..3
  const int quad = lane >> 4;
  const int r16  = lane & 15;

  const int NT = K / 64;

  // XCD-aware chunked swizzle on linear block id (gridDim.x % 8 == 0).
  const int nwg = gridDim.x;
  const int id  = blockIdx.x;
  const int sid = (id & 7) * (nwg >> 3) + (id >> 3);
  const int by  = sid / NTN;
  const int bx  = sid % NTN;
  const int aRowBase = by * 256;
  const int bColBase = bx * BN;

  f32x4 zero = {0.f, 0.f, 0.f, 0.f};
  f32x4 acc[8][2 * NR];
#pragma unroll
  for (int i = 0; i < 8; ++i)
#pragma unroll
    for (int j = 0; j < 2 * NR; ++j) acc[i][j] = zero;

  // --- staging: one half-tile (128 rows A / BHROW rows B) per call.
  // LDS dest linear (wave-uniform base + lane*16); global source pre-swizzled
  // so LDS content is swizzled: chunk(row,slot) holds global col-chunk
  // slot ^ (row&7).
  auto stageA = [&](int dbuf, int h, int t) {
    const int tt = t < NT ? t : NT - 1;
    const int k0 = tt * 64;
#pragma unroll
    for (int i = 0; i < 2; ++i) {
      const int chunk = (i * 8 + wave) * 64 + lane;  // 0..1023
      const int row = chunk >> 3;                    // 0..127
      const int slot = chunk & 7;
      const int gc = (slot ^ (row & 7)) * 8;
      gld_lds16(A + (size_t)(aRowBase + h * 128 + row) * K + k0 + gc,
                &As[dbuf][h * 8192 + (i * 8 + wave) * 512]);
    }
  };
  auto stageB = [&](int dbuf, int h, int t) {
    const int tt = t < NT ? t : NT - 1;
    const int k0 = tt * 64;
    if constexpr (BN == 256) {
#pragma unroll
      for (int i = 0; i < 2; ++i) {
        const int chunk = (i * 8 + wave) * 64 + lane;
        const int row = chunk >> 3;
        const int slot = chunk & 7;
        const int gc = (slot ^ (row & 7)) * 8;
        gld_lds16(Bm + (size_t)(bColBase + h * 128 + row) * K + k0 + gc,
                  &Bs[dbuf][h * 8192 + (i * 8 + wave) * 512]);
      }
    } else {
      const int chunk = wave * 64 + lane;  // 0..511
      const int row = chunk >> 3;          // 0..63
      const int slot = chunk & 7;
      const int gc = (slot ^ (row & 7)) * 8;
      gld_lds16(Bm + (size_t)(bColBase + h * 64 + row) * K + k0 + gc,
                &Bs[dbuf][h * 4096 + wave * 512]);
    }
  };

  bf16x8 af[4][2];      // current A half fragments
  bf16x8 b0[NR][2];     // B half-0 fragments (quadrant n=0)
  bf16x8 b1[NR][2];     // B half-1 fragments (quadrant n=1)

  auto readA = [&](int sbuf, int mh) {
#pragma unroll
    for (int mr = 0; mr < 4; ++mr)
#pragma unroll
      for (int kk = 0; kk < 2; ++kk) {
        const int row = mh * 128 + wm * 64 + mr * 16 + r16;
        const int slot = (kk * 4 + quad) ^ (r16 & 7);
        af[mr][kk] = *(const bf16x8*)&As[sbuf][row * 64 + slot * 8];
      }
  };
  auto readB = [&](int sbuf, int nh, bf16x8 (&bf)[NR][2]) {
#pragma unroll
    for (int nr = 0; nr < NR; ++nr)
#pragma unroll
      for (int kk = 0; kk < 2; ++kk) {
        const int row = nh * BHROW + wn * (BN / 8) + nr * 16 + r16;
        const int slot = (kk * 4 + quad) ^ (r16 & 7);
        bf[nr][kk] = *(const bf16x8*)&Bs[sbuf][row * 64 + slot * 8];
      }
  };

  // --- prologue: issue A0(0),A1(0),B0(0),B1(0),A0(1); drain through B0(0).
  stageA(0, 0, 0);
  stageA(0, 1, 0);
  stageB(0, 0, 0);
  stageB(0, 1, 0);
  stageA(1, 0, 1);
  if constexpr (BN == 256) VMCNT(4); else VMCNT(3);
  BAR();

  for (int t = 0; t < NT; ++t) {
    const int buf = t & 1, nbuf = buf ^ 1;

    // P1 (m0,n0): read A half0 + B half0; stage A1(t+1).
    readA(buf, 0);
    readB(buf, 0, b0);
    stageA(nbuf, 1, t + 1);
    BAR();
    MMA_PHASE(0, 0, b0);
    VMCNT(4);  // gate P2's B1(t) read (leaves A0(t+1), A1(t+1) in flight)
    BAR();

    // P2 (m0,n1): read B half1 (A reused from regs); stage B0(t+1).
    readB(buf, 1, b1);
    stageB(nbuf, 0, t + 1);
    BAR();
    MMA_PHASE(0, 1, b1);
    BAR();  // no wait: P3's A1(t) is older than B1(t), already drained

    // P3 (m1,n0): read A half1 (B0 reused from regs); stage B1(t+1).
    readA(buf, 1);
    stageB(nbuf, 1, t + 1);
    BAR();
    MMA_PHASE(1, 0, b0);
    BAR();  // no wait: P4 reads nothing from LDS

    // P4 (m1,n1): no reads; stage A0(t+2) into buf (A0 region free since P1).
    stageA(buf, 0, t + 2);
    BAR();
    MMA_PHASE(1, 1, b1);
    // gate next tile's P1 reads: drain A0(t+1), B0(t+1);
    // leaves B1(t+1), A0(t+2) in flight.
    if constexpr (BN == 256) VMCNT(4); else VMCNT(3);
    BAR();
  }
  VMCNT(0);  // hygiene before exit

  // --- epilogue: C write.
#pragma unroll
  for (int mi = 0; mi < 8; ++mi) {
    const int mh = mi >> 2, mr = mi & 3;
#pragma unroll
    for (int ni = 0; ni < 2 * NR; ++ni) {
      const int nh = ni / NR, nr = ni % NR;
      const int rowb = aRowBase + mh * 128 + wm * 64 + mr * 16 + quad * 4;
      const int col  = bColBase +
                       (BN == 256 ? nh * 128 + wn * 32 + nr * 16
                                  : nh * 64 + wn * 16) + r16;
#pragma unroll
      for (int reg = 0; reg < 4; ++reg) {
        const float v = acc[mi][ni][reg];
        const int m = rowb + reg;
        if (MODE == 1) {
          cout[(size_t)m * DOUT + col] = v;
        } else {
          if (col < 2048) {
            qbf[(size_t)m * DOUT + col] = f2bf(v * QSCALE);
          } else if (col < 2560) {
            const int gg = (col - 2048) >> 6, d = col & 63;
            const int b = m >> 11, s = m & 2047;
            const size_t idx = ((size_t)(b * NKV + gg) * S_ + s) * HD + d;
            kbf[idx]  = f2bf(v);
            kout[idx] = v;
          } else {
            const int gg = (col - 2560) >> 6, d = col & 63;
            const int b = m >> 11, s = m & 2047;
            vtbf[((size_t)(b * NKV + gg) * HD + d) * S_ + s]  = f2bf(v);
            vout[((size_t)(b * NKV + gg) * S_ + s) * HD + d] = v;
          }
        }
      }
    }
  }
}

// Flash attention, causal, m=0 softmax, in-register P (S^T operand-swap).
// 8 waves: group 0 (waves 0-3) = heavy tile (63-pairI), group 1 = light tile
// (pairI); wave = one head. K/V double-buffered via global_load_lds with
// prefetch-before-compute.
__global__ __launch_bounds__(512, 4) void attn_kernel(
    const unsigned short* __restrict__ Q,   // [B*S][DOUT] bf16 (scaled)
    const unsigned short* __restrict__ Kb,  // [B*NKV][S][HD] bf16
    const unsigned short* __restrict__ VT,  // [B*NKV][HD][S] bf16
    unsigned short* __restrict__ ctx) {     // [B*S][DOUT] bf16
  __shared__ unsigned short Kbuf[2][4096];  // 64 keys x 64 d, XOR-swizzled
  __shared__ unsigned short Vbuf[2][4096];  // 64 d x 64 keys, XOR-swizzled

  const int tid  = threadIdx.x;
  const int lane = tid & 63;
  const int wave = tid >> 6;   // 0..7
  const int grp  = wave >> 2;  // 0 = heavy tile, 1 = light tile
  const int hw   = wave & 3;
  const int quad = lane >> 4;
  const int r16  = lane & 15;
  const int g    = blockIdx.y;
  const int b    = blockIdx.z;
  const int h    = g * 4 + hw;
  const int pairI = blockIdx.x;  // 0..31, heavy-first
  const int q0     = grp ? pairI * 32 : (63 - pairI) * 32;
  const int nT_own = grp ? pairI / 2 + 1 : (63 - pairI) / 2 + 1;
  const int nTa    = (63 - pairI) / 2 + 1;  // block loop bound

  const unsigned short* Kh  = Kb + (size_t)(b * NKV + g) * S_ * HD;
  const unsigned short* VTh = VT + (size_t)(b * NKV + g) * HD * S_;

  const int srow   = lane >> 3;
  const int schunk = (lane & 7) ^ srow;

  // Q fragments (B-operand of S^T MFMA; same layout as A-operand)
  bf16x8 aq[2][2];
#pragma unroll
  for (int mt = 0; mt < 2; ++mt)
#pragma unroll
    for (int kk = 0; kk < 2; ++kk)
      aq[mt][kk] = *(const bf16x8*)(Q + (size_t)(b * S_ + q0 + mt * 16 + r16) * DOUT +
                                    h * HD + kk * 32 + quad * 8);

  bf16x4 ones4;
#pragma unroll
  for (int i = 0; i < 4; ++i) ones4[i] = (short)0x3F80;

  f32x4 zero = {0.f, 0.f, 0.f, 0.f};
  f32x4 o[2][4];  // [mt][dt]; C layout: row=q=quad*4+r, col=d=dt*16+r16
  f32x4 l[2];
#pragma unroll
  for (int mt = 0; mt < 2; ++mt) {
    l[mt] = zero;
#pragma unroll
    for (int dt = 0; dt < 4; ++dt) o[mt][dt] = zero;
  }

  // each wave stages one 8-row segment of K and of V^T (wave-uniform base)
  auto stage = [&](int buf, int kt) {
    const int kbase = kt * 64;
    gld_lds16(Kh + (size_t)(kbase + wave * 8 + srow) * HD + schunk * 8,
              &Kbuf[buf][wave * 512]);
    gld_lds16(VTh + (size_t)(wave * 8 + srow) * S_ + kbase + schunk * 8,
              &Vbuf[buf][wave * 512]);
  };

  stage(0, 0);
  __syncthreads();

  for (int kt = 0; kt < nTa; ++kt) {
    const int buf = kt & 1;
    if (kt + 1 < nTa) stage(buf ^ 1, kt + 1);

    if (kt < nT_own) {
      // K fragments: A-operand of S^T MFMA (m=key=r16 within tile nt)
      bf16x8 bk[4][2];
#pragma unroll
      for (int nt = 0; nt < 4; ++nt)
#pragma unroll
        for (int kk = 0; kk < 2; ++kk) {
          const int seg = nt * 2 + (r16 >> 3), r = r16 & 7;
          const int slot = (kk * 4 + quad) ^ r;
          bk[nt][kk] = *(const bf16x8*)&Kbuf[buf][seg * 512 + r * 64 + slot * 8];
        }

      const bool last = (kt == nT_own - 1);
#pragma unroll
      for (int mt = 0; mt < 2; ++mt) {
        // S^T = K.Q^T
        f32x4 st[4];
#pragma unroll
        for (int nt = 0; nt < 4; ++nt) st[nt] = zero;
#pragma unroll
        for (int kk = 0; kk < 2; ++kk)
#pragma unroll
          for (int nt = 0; nt < 4; ++nt)
            st[nt] = __builtin_amdgcn_mfma_f32_16x16x32_bf16(bk[nt][kk], aq[mt][kk], st[nt], 0, 0, 0);

        // mask + exp2 -> P A-fragments (K=16 layout), truncating bf16 pack
        bf16x4 pf[4];
#pragma unroll
        for (int nt = 0; nt < 4; ++nt) {
#pragma unroll
          for (int r = 0; r < 4; ++r) {
            float s = st[nt][r];
            if (last) {
              const int key = kt * 64 + nt * 16 + quad * 4 + r;
              const int row = q0 + mt * 16 + r16;
              if (key > row) s = -1e38f;
            }
            const float p = __builtin_amdgcn_exp2f(s);
            pf[nt][r] = (short)(__float_as_uint(p) >> 16);
          }
        }
        // row-sums via ones-MFMA, then PV with just-in-time V fragments
#pragma unroll
        for (int nt = 0; nt < 4; ++nt) l[mt] = mfma16(pf[nt], ones4, l[mt]);
#pragma unroll
        for (int dt = 0; dt < 4; ++dt) {
          const int seg = dt * 2 + (r16 >> 3), r = r16 & 7;
#pragma unroll
          for (int nt = 0; nt < 4; ++nt) {
            const int slot = (nt * 2 + (quad >> 1)) ^ r;
            bf16x4 bv = *(const bf16x4*)&Vbuf[buf][seg * 512 + r * 64 + slot * 8 + (quad & 1) * 4];
            o[mt][dt] = mfma16(pf[nt], bv, o[mt][dt]);
          }
        }
      }
    }

    __syncthreads();  // prefetch aged a full compute phase; swap buffers
  }

#pragma unroll
  for (int mt = 0; mt < 2; ++mt) {
    f32x4 rl;
#pragma unroll
    for (int r = 0; r < 4; ++r) rl[r] = __builtin_amdgcn_rcpf(l[mt][r]);
#pragma unroll
    for (int dt = 0; dt < 4; ++dt)
#pragma unroll
      for (int r = 0; r < 4; ++r) {
        const int qq = q0 + mt * 16 + quad * 4 + r;
        ctx[(size_t)(b * S_ + qq) * DOUT + h * HD + dt * 16 + r16] =
            f2bf(o[mt][dt][r] * rl[r]);
      }
  }
}

extern "C" void kernel_launch(void* const* d_in, const int* in_sizes, int n_in,
                              void* d_out, int out_size, void* d_ws, size_t ws_size,
                              hipStream_t stream) {
  const float* x  = (const float*)d_in[0];
  const float* Wq = (const float*)d_in[1];
  const float* Wk = (const float*)d_in[2];
  const float* Wv = (const float*)d_in[3];
  const float* Wo = (const float*)d_in[4];

  float* out  = (float*)d_out;
  float* keys = out + (size_t)B_ * S_ * DOUT;
  float* vals = keys + (size_t)B_ * NKV * S_ * HD;

  unsigned short* xbf  = (unsigned short*)d_ws;
  unsigned short* wqkv = xbf  + (size_t)B_ * S_ * DIN;
  unsigned short* wobf = wqkv + (size_t)NQKV * DIN;
  unsigned short* qbf  = wobf + (size_t)DIN * DOUT;
  unsigned short* kbf  = qbf  + (size_t)B_ * S_ * DOUT;
  unsigned short* vtbf = kbf  + (size_t)B_ * NKV * S_ * HD;
  unsigned short* ctx  = vtbf + (size_t)B_ * NKV * S_ * HD;

  cvt_all<<<dim3(4718592 / 256), dim3(256), 0, stream>>>(x, Wq, Wk, Wv, Wo,
                                                         xbf, wqkv, wobf);

  // QKV: M=4096, N=3072, 256x256 tiles -> 16x12 = 192 blocks (one round).
  gemm8p<0, 256, 12><<<dim3(192), dim3(512), 0, stream>>>(
      xbf, wqkv, DIN, qbf, kbf, vtbf, keys, vals, nullptr);

  attn_kernel<<<dim3(32, NKV, B_), dim3(512), 0, stream>>>(qbf, kbf, vtbf, ctx);

  // Wo: M=4096, N=2048, 256x128 tiles -> 16x16 = 256 blocks (100% coverage).
  gemm8p<1, 128, 16><<<dim3(256), dim3(512), 0, stream>>>(
      ctx, wobf, DOUT, nullptr, nullptr, nullptr, nullptr, nullptr, out);
}

// Round 3
// 318.876 us; speedup vs baseline: 1.0309x; 1.0042x over previous
//
#include <hip/hip_runtime.h>

// GQA fused pipeline, bf16 MFMA, gfx950.
// cvt(fp32->bf16) -> fused QKV GEMM (256-tile 4-phase counted-vmcnt schedule,
// T2 swizzle + T5 setprio, clobber-free waits) -> flash attention (unchanged)
// -> Wo GEMM (same schedule, 256x128 tile for full-grid coverage).

#define B_   2
#define S_   2048
#define DIN  2048
#define NH   32
#define NKV  8
#define HD   64
#define DOUT 2048
#define NQKV 3072

#define QSCALE 0.18033688f  // 0.125 * log2(e), folded into Q

typedef short bf16x8 __attribute__((ext_vector_type(8)));
typedef short bf16x4 __attribute__((ext_vector_type(4)));
typedef float f32x4  __attribute__((ext_vector_type(4)));

__device__ __forceinline__ unsigned short f2bf(float f) {
  unsigned int u = __float_as_uint(f);
  u += 0x7fff + ((u >> 16) & 1);  // RNE
  return (unsigned short)(u >> 16);
}

__device__ __forceinline__ f32x4 mfma16(bf16x4 a, bf16x4 b, f32x4 c) {
#if __has_builtin(__builtin_amdgcn_mfma_f32_16x16x16bf16_1k)
  return __builtin_amdgcn_mfma_f32_16x16x16bf16_1k(a, b, c, 0, 0, 0);
#else
  asm volatile("v_mfma_f32_16x16x16_bf16 %0, %1, %2, %0" : "+v"(c) : "v"(a), "v"(b));
  return c;
#endif
}

__device__ __forceinline__ void gld_lds16(const void* gptr, void* lptr) {
  __builtin_amdgcn_global_load_lds(
      (const __attribute__((address_space(1))) unsigned int*)gptr,
      (__attribute__((address_space(3))) unsigned int*)lptr,
      16, 0, 0);
}

// Raw barrier: NO memory clobber. A "memory" clobber makes the backend's
// waitcnt pass treat the asm as a full fence and drain vmcnt(0) -> defeats
// the counted-vmcnt pipeline (m141-style 22-waitcnt collapse, ~510 TF).
#define BAR() __builtin_amdgcn_s_barrier()

// Bare counted wait (no clobber) + sched_barrier(0) so no later LDS read can
// be scheduled above the wait (the only stale-read hazard once clobbers are
// gone; everything else is ordered by the side-effecting gld_lds intrinsics).
#define VMCNT(n)                                        \
  do {                                                  \
    asm volatile("s_waitcnt vmcnt(" #n ")");            \
    __builtin_amdgcn_sched_barrier(0);                  \
  } while (0)

// single conversion kernel for all 5 tensors (boundaries multiples of 256).
__global__ __launch_bounds__(256) void cvt_all(
    const float* __restrict__ x,  const float* __restrict__ Wq,
    const float* __restrict__ Wk, const float* __restrict__ Wv,
    const float* __restrict__ Wo,
    unsigned short* __restrict__ xbf, unsigned short* __restrict__ wqkv,
    unsigned short* __restrict__ wobf) {
  int i = blockIdx.x * blockDim.x + threadIdx.x;
  const float* src; unsigned short* dst; int off;
  if (i < 2097152)      { src = x;  dst = xbf;                  off = i; }
  else if (i < 3145728) { src = Wq; dst = wqkv;                 off = i - 2097152; }
  else if (i < 3407872) { src = Wk; dst = wqkv + 2048 * 2048;   off = i - 3145728; }
  else if (i < 3670016) { src = Wv; dst = wqkv + 2560 * 2048;   off = i - 3407872; }
  else                  { src = Wo; dst = wobf;                 off = i - 3670016; }
  float4 f = ((const float4*)src)[off];
  ushort4 o;
  o.x = f2bf(f.x); o.y = f2bf(f.y); o.z = f2bf(f.z); o.w = f2bf(f.w);
  ((ushort4*)dst)[off] = o;
}

// C = A @ B^T, 256x(BN) tile, BK=64, 8 waves (2 M x 4 N), 512 threads.
// 4 phases per K-tile (quadrants (0,0),(0,1),(1,0),(1,1)); per phase:
// {ds_read new frags; issue 1 half-stage; barrier; setprio(1) MFMA cluster
// setprio(0); [counted vmcnt at P1/P4]; barrier}. vmcnt never 0 in loop.
// MFMA cluster kk-outer: 8 independent MFMAs between dependent acc pairs.
#define MMA_PHASE(MH, NHH, BF)                                                  \
  do {                                                                          \
    __builtin_amdgcn_s_setprio(1);                                              \
    _Pragma("unroll")                                                           \
    for (int kk = 0; kk < 2; ++kk)                                              \
      _Pragma("unroll")                                                         \
      for (int mr = 0; mr < 4; ++mr)                                            \
        _Pragma("unroll")                                                       \
        for (int nr = 0; nr < NR; ++nr)                                         \
          acc[(MH) * 4 + mr][(NHH) * NR + nr] =                                 \
              __builtin_amdgcn_mfma_f32_16x16x32_bf16(                          \
                  af[mr][kk], BF[nr][kk], acc[(MH) * 4 + mr][(NHH) * NR + nr],  \
                  0, 0, 0);                                                     \
    __builtin_amdgcn_s_setprio(0);                                              \
  } while (0)

template <int MODE, int BN, int NTN>
__global__ __launch_bounds__(512, 2) void gemm8p(
    const unsigned short* __restrict__ A,
    const unsigned short* __restrict__ Bm,
    int K,
    unsigned short* __restrict__ qbf,
    unsigned short* __restrict__ kbf,
    unsigned short* __restrict__ vtbf,
    float* __restrict__ kout,
    float* __restrict__ vout,
    float* __restrict__ cout) {
  constexpr int NR = BN / 128;        // B fragments per quadrant (2 or 1)
  constexpr int BHROW = BN / 2;       // rows per B half-tile
  __shared__ unsigned short As[2][256 * 64];
  __shared__ unsigned short Bs[2][BN * 64];

  const int tid  = threadIdx.x;
  const int lane = tid & 63;
  const int wave = tid >> 6;  // 0..7
  const int wm   = wave >> 2; // 0..1
  const int wn   = wave & 3;  // 0..3
  const int quad = lane >> 4;
  const int r16  = lane & 15;

  const int NT = K / 64;

  // XCD-aware chunked swizzle on linear block id (gridDim.x % 8 == 0).
  const int nwg = gridDim.x;
  const int id  = blockIdx.x;
  const int sid = (id & 7) * (nwg >> 3) + (id >> 3);
  const int by  = sid / NTN;
  const int bx  = sid % NTN;
  const int aRowBase = by * 256;
  const int bColBase = bx * BN;

  f32x4 zero = {0.f, 0.f, 0.f, 0.f};
  f32x4 acc[8][2 * NR];
#pragma unroll
  for (int i = 0; i < 8; ++i)
#pragma unroll
    for (int j = 0; j < 2 * NR; ++j) acc[i][j] = zero;

  // --- staging: one half-tile (128 rows A / BHROW rows B) per call.
  // LDS dest linear (wave-uniform base + lane*16); global source pre-swizzled
  // so LDS content is swizzled: chunk(row,slot) holds global col-chunk
  // slot ^ (row&7).
  auto stageA = [&](int dbuf, int h, int t) {
    const int tt = t < NT ? t : NT - 1;
    const int k0 = tt * 64;
#pragma unroll
    for (int i = 0; i < 2; ++i) {
      const int chunk = (i * 8 + wave) * 64 + lane;  // 0..1023
      const int row = chunk >> 3;                    // 0..127
      const int slot = chunk & 7;
      const int gc = (slot ^ (row & 7)) * 8;
      gld_lds16(A + (size_t)(aRowBase + h * 128 + row) * K + k0 + gc,
                &As[dbuf][h * 8192 + (i * 8 + wave) * 512]);
    }
  };
  auto stageB = [&](int dbuf, int h, int t) {
    const int tt = t < NT ? t : NT - 1;
    const int k0 = tt * 64;
    if constexpr (BN == 256) {
#pragma unroll
      for (int i = 0; i < 2; ++i) {
        const int chunk = (i * 8 + wave) * 64 + lane;
        const int row = chunk >> 3;
        const int slot = chunk & 7;
        const int gc = (slot ^ (row & 7)) * 8;
        gld_lds16(Bm + (size_t)(bColBase + h * 128 + row) * K + k0 + gc,
                  &Bs[dbuf][h * 8192 + (i * 8 + wave) * 512]);
      }
    } else {
      const int chunk = wave * 64 + lane;  // 0..511
      const int row = chunk >> 3;          // 0..63
      const int slot = chunk & 7;
      const int gc = (slot ^ (row & 7)) * 8;
      gld_lds16(Bm + (size_t)(bColBase + h * 64 + row) * K + k0 + gc,
                &Bs[dbuf][h * 4096 + wave * 512]);
    }
  };

  bf16x8 af[4][2];      // current A half fragments
  bf16x8 b0[NR][2];     // B half-0 fragments (quadrant n=0)
  bf16x8 b1[NR][2];     // B half-1 fragments (quadrant n=1)

  auto readA = [&](int sbuf, int mh) {
#pragma unroll
    for (int mr = 0; mr < 4; ++mr)
#pragma unroll
      for (int kk = 0; kk < 2; ++kk) {
        const int row = mh * 128 + wm * 64 + mr * 16 + r16;
        const int slot = (kk * 4 + quad) ^ (r16 & 7);
        af[mr][kk] = *(const bf16x8*)&As[sbuf][row * 64 + slot * 8];
      }
  };
  auto readB = [&](int sbuf, int nh, bf16x8 (&bf)[NR][2]) {
#pragma unroll
    for (int nr = 0; nr < NR; ++nr)
#pragma unroll
      for (int kk = 0; kk < 2; ++kk) {
        const int row = nh * BHROW + wn * (BN / 8) + nr * 16 + r16;
        const int slot = (kk * 4 + quad) ^ (r16 & 7);
        bf[nr][kk] = *(const bf16x8*)&Bs[sbuf][row * 64 + slot * 8];
      }
  };

  // --- prologue: issue A0(0),A1(0),B0(0),B1(0),A0(1); drain through B0(0).
  stageA(0, 0, 0);
  stageA(0, 1, 0);
  stageB(0, 0, 0);
  stageB(0, 1, 0);
  stageA(1, 0, 1);
  if constexpr (BN == 256) VMCNT(4); else VMCNT(3);
  BAR();

  for (int t = 0; t < NT; ++t) {
    const int buf = t & 1, nbuf = buf ^ 1;

    // P1 (m0,n0): read A half0 + B half0; stage A1(t+1).
    readA(buf, 0);
    readB(buf, 0, b0);
    stageA(nbuf, 1, t + 1);
    BAR();
    MMA_PHASE(0, 0, b0);
    // gate P2's B1(t) read (leaves A0(t+1), A1(t+1) in flight)
    if constexpr (BN == 256) VMCNT(4); else VMCNT(3);
    BAR();

    // P2 (m0,n1): read B half1 (A reused from regs); stage B0(t+1).
    readB(buf, 1, b1);
    stageB(nbuf, 0, t + 1);
    BAR();
    MMA_PHASE(0, 1, b1);
    BAR();  // no wait: P3's A1(t) is older than B1(t), already drained

    // P3 (m1,n0): read A half1 (B0 reused from regs); stage B1(t+1).
    readA(buf, 1);
    stageB(nbuf, 1, t + 1);
    BAR();
    MMA_PHASE(1, 0, b0);
    BAR();  // no wait: P4 reads nothing from LDS

    // P4 (m1,n1): no reads; stage A0(t+2) into buf (A0 region free since P1).
    stageA(buf, 0, t + 2);
    BAR();
    MMA_PHASE(1, 1, b1);
    // gate next tile's P1 reads: drain A1(t+1), B0(t+1);
    // leaves B1(t+1), A0(t+2) in flight.
    if constexpr (BN == 256) VMCNT(4); else VMCNT(3);
    BAR();
  }
  VMCNT(0);  // hygiene before exit

  // --- epilogue: C write.
#pragma unroll
  for (int mi = 0; mi < 8; ++mi) {
    const int mh = mi >> 2, mr = mi & 3;
#pragma unroll
    for (int ni = 0; ni < 2 * NR; ++ni) {
      const int nh = ni / NR, nr = ni % NR;
      const int rowb = aRowBase + mh * 128 + wm * 64 + mr * 16 + quad * 4;
      const int col  = bColBase +
                       (BN == 256 ? nh * 128 + wn * 32 + nr * 16
                                  : nh * 64 + wn * 16) + r16;
#pragma unroll
      for (int reg = 0; reg < 4; ++reg) {
        const float v = acc[mi][ni][reg];
        const int m = rowb + reg;
        if (MODE == 1) {
          cout[(size_t)m * DOUT + col] = v;
        } else {
          if (col < 2048) {
            qbf[(size_t)m * DOUT + col] = f2bf(v * QSCALE);
          } else if (col < 2560) {
            const int gg = (col - 2048) >> 6, d = col & 63;
            const int b = m >> 11, s = m & 2047;
            const size_t idx = ((size_t)(b * NKV + gg) * S_ + s) * HD + d;
            kbf[idx]  = f2bf(v);
            kout[idx] = v;
          } else {
            const int gg = (col - 2560) >> 6, d = col & 63;
            const int b = m >> 11, s = m & 2047;
            vtbf[((size_t)(b * NKV + gg) * HD + d) * S_ + s]  = f2bf(v);
            vout[((size_t)(b * NKV + gg) * S_ + s) * HD + d] = v;
          }
        }
      }
    }
  }
}

// Flash attention, causal, m=0 softmax, in-register P (S^T operand-swap).
// 8 waves: group 0 (waves 0-3) = heavy tile (63-pairI), group 1 = light tile
// (pairI); wave = one head. K/V double-buffered via global_load_lds with
// prefetch-before-compute.
__global__ __launch_bounds__(512, 4) void attn_kernel(
    const unsigned short* __restrict__ Q,   // [B*S][DOUT] bf16 (scaled)
    const unsigned short* __restrict__ Kb,  // [B*NKV][S][HD] bf16
    const unsigned short* __restrict__ VT,  // [B*NKV][HD][S] bf16
    unsigned short* __restrict__ ctx) {     // [B*S][DOUT] bf16
  __shared__ unsigned short Kbuf[2][4096];  // 64 keys x 64 d, XOR-swizzled
  __shared__ unsigned short Vbuf[2][4096];  // 64 d x 64 keys, XOR-swizzled

  const int tid  = threadIdx.x;
  const int lane = tid & 63;
  const int wave = tid >> 6;   // 0..7
  const int grp  = wave >> 2;  // 0 = heavy tile, 1 = light tile
  const int hw   = wave & 3;
  const int quad = lane >> 4;
  const int r16  = lane & 15;
  const int g    = blockIdx.y;
  const int b    = blockIdx.z;
  const int h    = g * 4 + hw;
  const int pairI = blockIdx.x;  // 0..31, heavy-first
  const int q0     = grp ? pairI * 32 : (63 - pairI) * 32;
  const int nT_own = grp ? pairI / 2 + 1 : (63 - pairI) / 2 + 1;
  const int nTa    = (63 - pairI) / 2 + 1;  // block loop bound

  const unsigned short* Kh  = Kb + (size_t)(b * NKV + g) * S_ * HD;
  const unsigned short* VTh = VT + (size_t)(b * NKV + g) * HD * S_;

  const int srow   = lane >> 3;
  const int schunk = (lane & 7) ^ srow;

  // Q fragments (B-operand of S^T MFMA; same layout as A-operand)
  bf16x8 aq[2][2];
#pragma unroll
  for (int mt = 0; mt < 2; ++mt)
#pragma unroll
    for (int kk = 0; kk < 2; ++kk)
      aq[mt][kk] = *(const bf16x8*)(Q + (size_t)(b * S_ + q0 + mt * 16 + r16) * DOUT +
                                    h * HD + kk * 32 + quad * 8);

  bf16x4 ones4;
#pragma unroll
  for (int i = 0; i < 4; ++i) ones4[i] = (short)0x3F80;

  f32x4 zero = {0.f, 0.f, 0.f, 0.f};
  f32x4 o[2][4];  // [mt][dt]; C layout: row=q=quad*4+r, col=d=dt*16+r16
  f32x4 l[2];
#pragma unroll
  for (int mt = 0; mt < 2; ++mt) {
    l[mt] = zero;
#pragma unroll
    for (int dt = 0; dt < 4; ++dt) o[mt][dt] = zero;
  }

  // each wave stages one 8-row segment of K and of V^T (wave-uniform base)
  auto stage = [&](int buf, int kt) {
    const int kbase = kt * 64;
    gld_lds16(Kh + (size_t)(kbase + wave * 8 + srow) * HD + schunk * 8,
              &Kbuf[buf][wave * 512]);
    gld_lds16(VTh + (size_t)(wave * 8 + srow) * S_ + kbase + schunk * 8,
              &Vbuf[buf][wave * 512]);
  };

  stage(0, 0);
  __syncthreads();

  for (int kt = 0; kt < nTa; ++kt) {
    const int buf = kt & 1;
    if (kt + 1 < nTa) stage(buf ^ 1, kt + 1);

    if (kt < nT_own) {
      // K fragments: A-operand of S^T MFMA (m=key=r16 within tile nt)
      bf16x8 bk[4][2];
#pragma unroll
      for (int nt = 0; nt < 4; ++nt)
#pragma unroll
        for (int kk = 0; kk < 2; ++kk) {
          const int seg = nt * 2 + (r16 >> 3), r = r16 & 7;
          const int slot = (kk * 4 + quad) ^ r;
          bk[nt][kk] = *(const bf16x8*)&Kbuf[buf][seg * 512 + r * 64 + slot * 8];
        }

      const bool last = (kt == nT_own - 1);
#pragma unroll
      for (int mt = 0; mt < 2; ++mt) {
        // S^T = K.Q^T
        f32x4 st[4];
#pragma unroll
        for (int nt = 0; nt < 4; ++nt) st[nt] = zero;
#pragma unroll
        for (int kk = 0; kk < 2; ++kk)
#pragma unroll
          for (int nt = 0; nt < 4; ++nt)
            st[nt] = __builtin_amdgcn_mfma_f32_16x16x32_bf16(bk[nt][kk], aq[mt][kk], st[nt], 0, 0, 0);

        // mask + exp2 -> P A-fragments (K=16 layout), truncating bf16 pack
        bf16x4 pf[4];
#pragma unroll
        for (int nt = 0; nt < 4; ++nt) {
#pragma unroll
          for (int r = 0; r < 4; ++r) {
            float s = st[nt][r];
            if (last) {
              const int key = kt * 64 + nt * 16 + quad * 4 + r;
              const int row = q0 + mt * 16 + r16;
              if (key > row) s = -1e38f;
            }
            const float p = __builtin_amdgcn_exp2f(s);
            pf[nt][r] = (short)(__float_as_uint(p) >> 16);
          }
        }
        // row-sums via ones-MFMA, then PV with just-in-time V fragments
#pragma unroll
        for (int nt = 0; nt < 4; ++nt) l[mt] = mfma16(pf[nt], ones4, l[mt]);
#pragma unroll
        for (int dt = 0; dt < 4; ++dt) {
          const int seg = dt * 2 + (r16 >> 3), r = r16 & 7;
#pragma unroll
          for (int nt = 0; nt < 4; ++nt) {
            const int slot = (nt * 2 + (quad >> 1)) ^ r;
            bf16x4 bv = *(const bf16x4*)&Vbuf[buf][seg * 512 + r * 64 + slot * 8 + (quad & 1) * 4];
            o[mt][dt] = mfma16(pf[nt], bv, o[mt][dt]);
          }
        }
      }
    }

    __syncthreads();  // prefetch aged a full compute phase; swap buffers
  }

#pragma unroll
  for (int mt = 0; mt < 2; ++mt) {
    f32x4 rl;
#pragma unroll
    for (int r = 0; r < 4; ++r) rl[r] = __builtin_amdgcn_rcpf(l[mt][r]);
#pragma unroll
    for (int dt = 0; dt < 4; ++dt)
#pragma unroll
      for (int r = 0; r < 4; ++r) {
        const int qq = q0 + mt * 16 + quad * 4 + r;
        ctx[(size_t)(b * S_ + qq) * DOUT + h * HD + dt * 16 + r16] =
            f2bf(o[mt][dt][r] * rl[r]);
      }
  }
}

extern "C" void kernel_launch(void* const* d_in, const int* in_sizes, int n_in,
                              void* d_out, int out_size, void* d_ws, size_t ws_size,
                              hipStream_t stream) {
  const float* x  = (const float*)d_in[0];
  const float* Wq = (const float*)d_in[1];
  const float* Wk = (const float*)d_in[2];
  const float* Wv = (const float*)d_in[3];
  const float* Wo = (const float*)d_in[4];

  float* out  = (float*)d_out;
  float* keys = out + (size_t)B_ * S_ * DOUT;
  float* vals = keys + (size_t)B_ * NKV * S_ * HD;

  unsigned short* xbf  = (unsigned short*)d_ws;
  unsigned short* wqkv = xbf  + (size_t)B_ * S_ * DIN;
  unsigned short* wobf = wqkv + (size_t)NQKV * DIN;
  unsigned short* qbf  = wobf + (size_t)DIN * DOUT;
  unsigned short* kbf  = qbf  + (size_t)B_ * S_ * DOUT;
  unsigned short* vtbf = kbf  + (size_t)B_ * NKV * S_ * HD;
  unsigned short* ctx  = vtbf + (size_t)B_ * NKV * S_ * HD;

  cvt_all<<<dim3(4718592 / 256), dim3(256), 0, stream>>>(x, Wq, Wk, Wv, Wo,
                                                         xbf, wqkv, wobf);

  // QKV: M=4096, N=3072, 256x256 tiles -> 16x12 = 192 blocks (one round).
  gemm8p<0, 256, 12><<<dim3(192), dim3(512), 0, stream>>>(
      xbf, wqkv, DIN, qbf, kbf, vtbf, keys, vals, nullptr);

  attn_kernel<<<dim3(32, NKV, B_), dim3(512), 0, stream>>>(qbf, kbf, vtbf, ctx);

  // Wo: M=4096, N=2048, 256x128 tiles -> 16x16 = 256 blocks (100% coverage).
  gemm8p<1, 128, 16><<<dim3(256), dim3(512), 0, stream>>>(
      ctx, wobf, DOUT, nullptr, nullptr, nullptr, nullptr, nullptr, out);
}

// Round 4
// 309.985 us; speedup vs baseline: 1.0605x; 1.0287x over previous
//
#include <hip/hip_runtime.h>

// GQA fused pipeline, bf16 MFMA, gfx950.
// cvt(fp32->bf16) -> fused QKV GEMM (m201-faithful 2-K-tile/8-phase
// counted-vmcnt schedule, T2 swizzle + T5 setprio) -> flash attention
// (unchanged) -> Wo GEMM (same schedule, 256x128 tile).

#define B_   2
#define S_   2048
#define DIN  2048
#define NH   32
#define NKV  8
#define HD   64
#define DOUT 2048
#define NQKV 3072

#define QSCALE 0.18033688f  // 0.125 * log2(e), folded into Q

typedef short bf16x8 __attribute__((ext_vector_type(8)));
typedef short bf16x4 __attribute__((ext_vector_type(4)));
typedef float f32x4  __attribute__((ext_vector_type(4)));

__device__ __forceinline__ unsigned short f2bf(float f) {
  unsigned int u = __float_as_uint(f);
  u += 0x7fff + ((u >> 16) & 1);  // RNE
  return (unsigned short)(u >> 16);
}

__device__ __forceinline__ f32x4 mfma16(bf16x4 a, bf16x4 b, f32x4 c) {
#if __has_builtin(__builtin_amdgcn_mfma_f32_16x16x16bf16_1k)
  return __builtin_amdgcn_mfma_f32_16x16x16bf16_1k(a, b, c, 0, 0, 0);
#else
  asm volatile("v_mfma_f32_16x16x16_bf16 %0, %1, %2, %0" : "+v"(c) : "v"(a), "v"(b));
  return c;
#endif
}

__device__ __forceinline__ void gld_lds16(const void* gptr, void* lptr) {
  __builtin_amdgcn_global_load_lds(
      (const __attribute__((address_space(1))) unsigned int*)gptr,
      (__attribute__((address_space(3))) unsigned int*)lptr,
      16, 0, 0);
}

#define BAR() __builtin_amdgcn_s_barrier()
#define SB()  __builtin_amdgcn_sched_barrier(0)
#define VMCNT(n) asm volatile("s_waitcnt vmcnt(" #n ")")

// single conversion kernel for all 5 tensors (boundaries multiples of 256).
__global__ __launch_bounds__(256) void cvt_all(
    const float* __restrict__ x,  const float* __restrict__ Wq,
    const float* __restrict__ Wk, const float* __restrict__ Wv,
    const float* __restrict__ Wo,
    unsigned short* __restrict__ xbf, unsigned short* __restrict__ wqkv,
    unsigned short* __restrict__ wobf) {
  int i = blockIdx.x * blockDim.x + threadIdx.x;
  const float* src; unsigned short* dst; int off;
  if (i < 2097152)      { src = x;  dst = xbf;                  off = i; }
  else if (i < 3145728) { src = Wq; dst = wqkv;                 off = i - 2097152; }
  else if (i < 3407872) { src = Wk; dst = wqkv + 2048 * 2048;   off = i - 3145728; }
  else if (i < 3670016) { src = Wv; dst = wqkv + 2560 * 2048;   off = i - 3407872; }
  else                  { src = Wo; dst = wobf;                 off = i - 3670016; }
  float4 f = ((const float4*)src)[off];
  ushort4 o;
  o.x = f2bf(f.x); o.y = f2bf(f.y); o.z = f2bf(f.z); o.w = f2bf(f.w);
  ((ushort4*)dst)[off] = o;
}

// C = A @ B^T, 256x(BN) tile, BK=64, 8 waves (2 M x 4 N), 512 threads.
// 2 K-tiles per iteration, 8 phases; one half-tile stage per phase.
// Stage ledger (iter i handles tiles e=2i, o=2i+1):
//   S1=A1(o)->buf1  S2=A0(e+2)->buf0 S3=B0(e+2)->buf0 S4=B1(e+2)->buf0
//   S5=A1(e+2)->buf0 S6=A0(o+2)->buf1 S7=B0(o+2)->buf1 S8=B1(o+2)->buf1
// vmcnt(W) at phases 4 & 8 ONLY (W=6 for BN=256, 4 for BN=128): each wait
// lands exactly the 4 half-tiles the next tile needs, leaves 3 stages in
// flight; min issue->consume slack = 3 phases. Never vmcnt(0) in loop.
#define MMA_PHASE(MH, NHH, BF)                                                  \
  do {                                                                          \
    __builtin_amdgcn_s_setprio(1);                                              \
    _Pragma("unroll")                                                           \
    for (int kk = 0; kk < 2; ++kk)                                              \
      _Pragma("unroll")                                                         \
      for (int mr = 0; mr < 4; ++mr)                                            \
        _Pragma("unroll")                                                       \
        for (int nr = 0; nr < NR; ++nr)                                         \
          acc[(MH) * 4 + mr][(NHH) * NR + nr] =                                 \
              __builtin_amdgcn_mfma_f32_16x16x32_bf16(                          \
                  af[mr][kk], BF[nr][kk], acc[(MH) * 4 + mr][(NHH) * NR + nr],  \
                  0, 0, 0);                                                     \
    __builtin_amdgcn_s_setprio(0);                                              \
  } while (0)

#define WAITW()                                   \
  do {                                            \
    if constexpr (BN == 256) VMCNT(6);            \
    else                     VMCNT(4);            \
  } while (0)

template <int MODE, int BN, int NTN>
__global__ __launch_bounds__(512, 2) void gemm8p(
    const unsigned short* __restrict__ A,
    const unsigned short* __restrict__ Bm,
    int K,
    unsigned short* __restrict__ qbf,
    unsigned short* __restrict__ kbf,
    unsigned short* __restrict__ vtbf,
    float* __restrict__ kout,
    float* __restrict__ vout,
    float* __restrict__ cout) {
  constexpr int NR = BN / 128;        // B fragments per quadrant (2 or 1)
  constexpr int BHROW = BN / 2;       // rows per B half-tile
  __shared__ unsigned short As[2][256 * 64];
  __shared__ unsigned short Bs[2][BN * 64];

  const int tid  = threadIdx.x;
  const int lane = tid & 63;
  const int wave = tid >> 6;  // 0..7
  const int wm   = wave >> 2; // 0..1
  const int wn   = wave & 3;  // 0..3
  const int quad = lane >> 4;
  const int r16  = lane & 15;

  const int NT = K / 64;

  // XCD-aware chunked swizzle on linear block id (gridDim.x % 8 == 0).
  const int nwg = gridDim.x;
  const int id  = blockIdx.x;
  const int sid = (id & 7) * (nwg >> 3) + (id >> 3);
  const int by  = sid / NTN;
  const int bx  = sid % NTN;
  const int aRowBase = by * 256;
  const int bColBase = bx * BN;

  f32x4 zero = {0.f, 0.f, 0.f, 0.f};
  f32x4 acc[8][2 * NR];
#pragma unroll
  for (int i = 0; i < 8; ++i)
#pragma unroll
    for (int j = 0; j < 2 * NR; ++j) acc[i][j] = zero;

  // --- staging: one half-tile (128 rows A / BHROW rows B) per call.
  // LDS dest linear; global source pre-swizzled so LDS holds chunk
  // slot ^ (row&7) (T2 both-sides swizzle, rule #21).
  auto stageA = [&](int dbuf, int h, int t) {
    const int tt = t < NT ? t : NT - 1;
    const int k0 = tt * 64;
#pragma unroll
    for (int i = 0; i < 2; ++i) {
      const int chunk = (i * 8 + wave) * 64 + lane;  // 0..1023
      const int row = chunk >> 3;                    // 0..127
      const int slot = chunk & 7;
      const int gc = (slot ^ (row & 7)) * 8;
      gld_lds16(A + (size_t)(aRowBase + h * 128 + row) * K + k0 + gc,
                &As[dbuf][h * 8192 + (i * 8 + wave) * 512]);
    }
  };
  auto stageB = [&](int dbuf, int h, int t) {
    const int tt = t < NT ? t : NT - 1;
    const int k0 = tt * 64;
    if constexpr (BN == 256) {
#pragma unroll
      for (int i = 0; i < 2; ++i) {
        const int chunk = (i * 8 + wave) * 64 + lane;
        const int row = chunk >> 3;
        const int slot = chunk & 7;
        const int gc = (slot ^ (row & 7)) * 8;
        gld_lds16(Bm + (size_t)(bColBase + h * 128 + row) * K + k0 + gc,
                  &Bs[dbuf][h * 8192 + (i * 8 + wave) * 512]);
      }
    } else {
      const int chunk = wave * 64 + lane;  // 0..511
      const int row = chunk >> 3;          // 0..63
      const int slot = chunk & 7;
      const int gc = (slot ^ (row & 7)) * 8;
      gld_lds16(Bm + (size_t)(bColBase + h * 64 + row) * K + k0 + gc,
                &Bs[dbuf][h * 4096 + wave * 512]);
    }
  };

  bf16x8 af[4][2];      // current A half fragments
  bf16x8 b0[NR][2];     // B half-0 fragments
  bf16x8 b1[NR][2];     // B half-1 fragments

  auto readA = [&](int sbuf, int mh) {
#pragma unroll
    for (int mr = 0; mr < 4; ++mr)
#pragma unroll
      for (int kk = 0; kk < 2; ++kk) {
        const int row = mh * 128 + wm * 64 + mr * 16 + r16;
        const int slot = (kk * 4 + quad) ^ (r16 & 7);
        af[mr][kk] = *(const bf16x8*)&As[sbuf][row * 64 + slot * 8];
      }
  };
  auto readB = [&](int sbuf, int nh, bf16x8 (&bf)[NR][2]) {
#pragma unroll
    for (int nr = 0; nr < NR; ++nr)
#pragma unroll
      for (int kk = 0; kk < 2; ++kk) {
        const int row = nh * BHROW + wn * (BN / 8) + nr * 16 + r16;
        const int slot = (kk * 4 + quad) ^ (r16 & 7);
        bf[nr][kk] = *(const bf16x8*)&Bs[sbuf][row * 64 + slot * 8];
      }
  };

  // --- prologue: tile0 full + tile1 {A0,B0,B1}; wait leaves last 3 stages.
  stageA(0, 0, 0);   // A0(0)
  stageB(0, 0, 0);   // B0(0)
  stageB(0, 1, 0);   // B1(0)
  stageA(0, 1, 0);   // A1(0)
  stageA(1, 0, 1);   // A0(1)
  stageB(1, 0, 1);   // B0(1)
  stageB(1, 1, 1);   // B1(1)
  WAITW();
  BAR(); SB();

  const int NIT = NT / 2;
  for (int i = 0; i < NIT; ++i) {
    const int e2 = 2 * i + 2, o2 = 2 * i + 3;

    // Ph1 (tile e, q00): read A0,B0 buf0; S1 = A1(o)->buf1.
    readA(0, 0); readB(0, 0, b0);
    stageA(1, 1, 2 * i + 1);
    BAR();
    MMA_PHASE(0, 0, b0);
    BAR(); SB();

    // Ph2 (e, q01): read B1 buf0; S2 = A0(e+2)->buf0.
    readB(0, 1, b1);
    stageA(0, 0, e2);
    BAR();
    MMA_PHASE(0, 1, b1);
    BAR(); SB();

    // Ph3 (e, q10): read A1 buf0; S3 = B0(e+2)->buf0.
    readA(0, 1);
    stageB(0, 0, e2);
    BAR();
    MMA_PHASE(1, 0, b0);
    BAR(); SB();

    // Ph4 (e, q11): no reads; S4 = B1(e+2)->buf0; counted wait.
    stageB(0, 1, e2);
    BAR();
    MMA_PHASE(1, 1, b1);
    WAITW();
    BAR(); SB();

    // Ph5 (tile o, q00): read A0,B0 buf1; S5 = A1(e+2)->buf0.
    readA(1, 0); readB(1, 0, b0);
    stageA(0, 1, e2);
    BAR();
    MMA_PHASE(0, 0, b0);
    BAR(); SB();

    // Ph6 (o, q01): read B1 buf1; S6 = A0(o+2)->buf1.
    readB(1, 1, b1);
    stageA(1, 0, o2);
    BAR();
    MMA_PHASE(0, 1, b1);
    BAR(); SB();

    // Ph7 (o, q10): read A1 buf1; S7 = B0(o+2)->buf1.
    readA(1, 1);
    stageB(1, 0, o2);
    BAR();
    MMA_PHASE(1, 0, b0);
    BAR(); SB();

    // Ph8 (o, q11): no reads; S8 = B1(o+2)->buf1; counted wait.
    stageB(1, 1, o2);
    BAR();
    MMA_PHASE(1, 1, b1);
    WAITW();
    BAR(); SB();
  }
  VMCNT(0);  // hygiene before exit

  // --- epilogue: C write.
#pragma unroll
  for (int mi = 0; mi < 8; ++mi) {
    const int mh = mi >> 2, mr = mi & 3;
#pragma unroll
    for (int ni = 0; ni < 2 * NR; ++ni) {
      const int nh = ni / NR, nr = ni % NR;
      const int rowb = aRowBase + mh * 128 + wm * 64 + mr * 16 + quad * 4;
      const int col  = bColBase +
                       (BN == 256 ? nh * 128 + wn * 32 + nr * 16
                                  : nh * 64 + wn * 16) + r16;
#pragma unroll
      for (int reg = 0; reg < 4; ++reg) {
        const float v = acc[mi][ni][reg];
        const int m = rowb + reg;
        if (MODE == 1) {
          cout[(size_t)m * DOUT + col] = v;
        } else {
          if (col < 2048) {
            qbf[(size_t)m * DOUT + col] = f2bf(v * QSCALE);
          } else if (col < 2560) {
            const int gg = (col - 2048) >> 6, d = col & 63;
            const int b = m >> 11, s = m & 2047;
            const size_t idx = ((size_t)(b * NKV + gg) * S_ + s) * HD + d;
            kbf[idx]  = f2bf(v);
            kout[idx] = v;
          } else {
            const int gg = (col - 2560) >> 6, d = col & 63;
            const int b = m >> 11, s = m & 2047;
            vtbf[((size_t)(b * NKV + gg) * HD + d) * S_ + s]  = f2bf(v);
            vout[((size_t)(b * NKV + gg) * S_ + s) * HD + d] = v;
          }
        }
      }
    }
  }
}

// Flash attention, causal, m=0 softmax, in-register P (S^T operand-swap).
// 8 waves: group 0 (waves 0-3) = heavy tile (63-pairI), group 1 = light tile
// (pairI); wave = one head. K/V double-buffered via global_load_lds with
// prefetch-before-compute.
__global__ __launch_bounds__(512, 4) void attn_kernel(
    const unsigned short* __restrict__ Q,   // [B*S][DOUT] bf16 (scaled)
    const unsigned short* __restrict__ Kb,  // [B*NKV][S][HD] bf16
    const unsigned short* __restrict__ VT,  // [B*NKV][HD][S] bf16
    unsigned short* __restrict__ ctx) {     // [B*S][DOUT] bf16
  __shared__ unsigned short Kbuf[2][4096];  // 64 keys x 64 d, XOR-swizzled
  __shared__ unsigned short Vbuf[2][4096];  // 64 d x 64 keys, XOR-swizzled

  const int tid  = threadIdx.x;
  const int lane = tid & 63;
  const int wave = tid >> 6;   // 0..7
  const int grp  = wave >> 2;  // 0 = heavy tile, 1 = light tile
  const int hw   = wave & 3;
  const int quad = lane >> 4;
  const int r16  = lane & 15;
  const int g    = blockIdx.y;
  const int b    = blockIdx.z;
  const int h    = g * 4 + hw;
  const int pairI = blockIdx.x;  // 0..31, heavy-first
  const int q0     = grp ? pairI * 32 : (63 - pairI) * 32;
  const int nT_own = grp ? pairI / 2 + 1 : (63 - pairI) / 2 + 1;
  const int nTa    = (63 - pairI) / 2 + 1;  // block loop bound

  const unsigned short* Kh  = Kb + (size_t)(b * NKV + g) * S_ * HD;
  const unsigned short* VTh = VT + (size_t)(b * NKV + g) * HD * S_;

  const int srow   = lane >> 3;
  const int schunk = (lane & 7) ^ srow;

  // Q fragments (B-operand of S^T MFMA; same layout as A-operand)
  bf16x8 aq[2][2];
#pragma unroll
  for (int mt = 0; mt < 2; ++mt)
#pragma unroll
    for (int kk = 0; kk < 2; ++kk)
      aq[mt][kk] = *(const bf16x8*)(Q + (size_t)(b * S_ + q0 + mt * 16 + r16) * DOUT +
                                    h * HD + kk * 32 + quad * 8);

  bf16x4 ones4;
#pragma unroll
  for (int i = 0; i < 4; ++i) ones4[i] = (short)0x3F80;

  f32x4 zero = {0.f, 0.f, 0.f, 0.f};
  f32x4 o[2][4];  // [mt][dt]; C layout: row=q=quad*4+r, col=d=dt*16+r16
  f32x4 l[2];
#pragma unroll
  for (int mt = 0; mt < 2; ++mt) {
    l[mt] = zero;
#pragma unroll
    for (int dt = 0; dt < 4; ++dt) o[mt][dt] = zero;
  }

  // each wave stages one 8-row segment of K and of V^T (wave-uniform base)
  auto stage = [&](int buf, int kt) {
    const int kbase = kt * 64;
    gld_lds16(Kh + (size_t)(kbase + wave * 8 + srow) * HD + schunk * 8,
              &Kbuf[buf][wave * 512]);
    gld_lds16(VTh + (size_t)(wave * 8 + srow) * S_ + kbase + schunk * 8,
              &Vbuf[buf][wave * 512]);
  };

  stage(0, 0);
  __syncthreads();

  for (int kt = 0; kt < nTa; ++kt) {
    const int buf = kt & 1;
    if (kt + 1 < nTa) stage(buf ^ 1, kt + 1);

    if (kt < nT_own) {
      // K fragments: A-operand of S^T MFMA (m=key=r16 within tile nt)
      bf16x8 bk[4][2];
#pragma unroll
      for (int nt = 0; nt < 4; ++nt)
#pragma unroll
        for (int kk = 0; kk < 2; ++kk) {
          const int seg = nt * 2 + (r16 >> 3), r = r16 & 7;
          const int slot = (kk * 4 + quad) ^ r;
          bk[nt][kk] = *(const bf16x8*)&Kbuf[buf][seg * 512 + r * 64 + slot * 8];
        }

      const bool last = (kt == nT_own - 1);
#pragma unroll
      for (int mt = 0; mt < 2; ++mt) {
        // S^T = K.Q^T
        f32x4 st[4];
#pragma unroll
        for (int nt = 0; nt < 4; ++nt) st[nt] = zero;
#pragma unroll
        for (int kk = 0; kk < 2; ++kk)
#pragma unroll
          for (int nt = 0; nt < 4; ++nt)
            st[nt] = __builtin_amdgcn_mfma_f32_16x16x32_bf16(bk[nt][kk], aq[mt][kk], st[nt], 0, 0, 0);

        // mask + exp2 -> P A-fragments (K=16 layout), truncating bf16 pack
        bf16x4 pf[4];
#pragma unroll
        for (int nt = 0; nt < 4; ++nt) {
#pragma unroll
          for (int r = 0; r < 4; ++r) {
            float s = st[nt][r];
            if (last) {
              const int key = kt * 64 + nt * 16 + quad * 4 + r;
              const int row = q0 + mt * 16 + r16;
              if (key > row) s = -1e38f;
            }
            const float p = __builtin_amdgcn_exp2f(s);
            pf[nt][r] = (short)(__float_as_uint(p) >> 16);
          }
        }
        // row-sums via ones-MFMA, then PV with just-in-time V fragments
#pragma unroll
        for (int nt = 0; nt < 4; ++nt) l[mt] = mfma16(pf[nt], ones4, l[mt]);
#pragma unroll
        for (int dt = 0; dt < 4; ++dt) {
          const int seg = dt * 2 + (r16 >> 3), r = r16 & 7;
#pragma unroll
          for (int nt = 0; nt < 4; ++nt) {
            const int slot = (nt * 2 + (quad >> 1)) ^ r;
            bf16x4 bv = *(const bf16x4*)&Vbuf[buf][seg * 512 + r * 64 + slot * 8 + (quad & 1) * 4];
            o[mt][dt] = mfma16(pf[nt], bv, o[mt][dt]);
          }
        }
      }
    }

    __syncthreads();  // prefetch aged a full compute phase; swap buffers
  }

#pragma unroll
  for (int mt = 0; mt < 2; ++mt) {
    f32x4 rl;
#pragma unroll
    for (int r = 0; r < 4; ++r) rl[r] = __builtin_amdgcn_rcpf(l[mt][r]);
#pragma unroll
    for (int dt = 0; dt < 4; ++dt)
#pragma unroll
      for (int r = 0; r < 4; ++r) {
        const int qq = q0 + mt * 16 + quad * 4 + r;
        ctx[(size_t)(b * S_ + qq) * DOUT + h * HD + dt * 16 + r16] =
            f2bf(o[mt][dt][r] * rl[r]);
      }
  }
}

extern "C" void kernel_launch(void* const* d_in, const int* in_sizes, int n_in,
                              void* d_out, int out_size, void* d_ws, size_t ws_size,
                              hipStream_t stream) {
  const float* x  = (const float*)d_in[0];
  const float* Wq = (const float*)d_in[1];
  const float* Wk = (const float*)d_in[2];
  const float* Wv = (const float*)d_in[3];
  const float* Wo = (const float*)d_in[4];

  float* out  = (float*)d_out;
  float* keys = out + (size_t)B_ * S_ * DOUT;
  float* vals = keys + (size_t)B_ * NKV * S_ * HD;

  unsigned short* xbf  = (unsigned short*)d_ws;
  unsigned short* wqkv = xbf  + (size_t)B_ * S_ * DIN;
  unsigned short* wobf = wqkv + (size_t)NQKV * DIN;
  unsigned short* qbf  = wobf + (size_t)DIN * DOUT;
  unsigned short* kbf  = qbf  + (size_t)B_ * S_ * DOUT;
  unsigned short* vtbf = kbf  + (size_t)B_ * NKV * S_ * HD;
  unsigned short* ctx  = vtbf + (size_t)B_ * NKV * S_ * HD;

  cvt_all<<<dim3(4718592 / 256), dim3(256), 0, stream>>>(x, Wq, Wk, Wv, Wo,
                                                         xbf, wqkv, wobf);

  // QKV: M=4096, N=3072, 256x256 tiles -> 16x12 = 192 blocks (one round).
  gemm8p<0, 256, 12><<<dim3(192), dim3(512), 0, stream>>>(
      xbf, wqkv, DIN, qbf, kbf, vtbf, keys, vals, nullptr);

  attn_kernel<<<dim3(32, NKV, B_), dim3(512), 0, stream>>>(qbf, kbf, vtbf, ctx);

  // Wo: M=4096, N=2048, 256x128 tiles -> 16x16 = 256 blocks (100% coverage).
  gemm8p<1, 128, 16><<<dim3(256), dim3(512), 0, stream>>>(
      ctx, wobf, DOUT, nullptr, nullptr, nullptr, nullptr, nullptr, out);
}

// Round 5
// 295.625 us; speedup vs baseline: 1.1120x; 1.0486x over previous
//
#include <hip/hip_runtime.h>

// GQA fused pipeline, bf16 MFMA, gfx950.
// cvt(fp32->bf16) -> fused QKV GEMM (2-K-tile/8-phase counted-vmcnt schedule,
// asm ds_read fragment loads, T2 swizzle + T5 setprio) -> flash attention
// (unchanged) -> Wo GEMM (same schedule, 256x128 tile).

#define B_   2
#define S_   2048
#define DIN  2048
#define NH   32
#define NKV  8
#define HD   64
#define DOUT 2048
#define NQKV 3072

#define QSCALE 0.18033688f  // 0.125 * log2(e), folded into Q

typedef short bf16x8 __attribute__((ext_vector_type(8)));
typedef short bf16x4 __attribute__((ext_vector_type(4)));
typedef float f32x4  __attribute__((ext_vector_type(4)));

__device__ __forceinline__ unsigned short f2bf(float f) {
  unsigned int u = __float_as_uint(f);
  u += 0x7fff + ((u >> 16) & 1);  // RNE
  return (unsigned short)(u >> 16);
}

__device__ __forceinline__ f32x4 mfma16(bf16x4 a, bf16x4 b, f32x4 c) {
#if __has_builtin(__builtin_amdgcn_mfma_f32_16x16x16bf16_1k)
  return __builtin_amdgcn_mfma_f32_16x16x16bf16_1k(a, b, c, 0, 0, 0);
#else
  asm volatile("v_mfma_f32_16x16x16_bf16 %0, %1, %2, %0" : "+v"(c) : "v"(a), "v"(b));
  return c;
#endif
}

__device__ __forceinline__ void gld_lds16(const void* gptr, void* lptr) {
  __builtin_amdgcn_global_load_lds(
      (const __attribute__((address_space(1))) unsigned int*)gptr,
      (__attribute__((address_space(3))) unsigned int*)lptr,
      16, 0, 0);
}

// Inline-asm LDS read: invisible to the backend's aliasing analysis, so no
// compiler-inserted `s_waitcnt vmcnt(0)` guarding against outstanding
// global_load_lds writes -- ordering is OUR ledger's job (barriers + counted
// vmcnt). Requires manual lgkmcnt(0)+sched_barrier(0) before consumption
// (rule #18).
__device__ __forceinline__ bf16x8 ds_read128(const unsigned short* p) {
  bf16x8 r;
  asm volatile("ds_read_b128 %0, %1"
               : "=v"(r)
               : "v"((const __attribute__((address_space(3))) unsigned short*)p));
  return r;
}

#define BAR() __builtin_amdgcn_s_barrier()
#define SB()  __builtin_amdgcn_sched_barrier(0)
#define VMCNT(n) asm volatile("s_waitcnt vmcnt(" #n ")")
#define LGKM0()                                   \
  do {                                            \
    asm volatile("s_waitcnt lgkmcnt(0)");         \
    __builtin_amdgcn_sched_barrier(0);            \
  } while (0)

// single conversion kernel for all 5 tensors (boundaries multiples of 256).
__global__ __launch_bounds__(256) void cvt_all(
    const float* __restrict__ x,  const float* __restrict__ Wq,
    const float* __restrict__ Wk, const float* __restrict__ Wv,
    const float* __restrict__ Wo,
    unsigned short* __restrict__ xbf, unsigned short* __restrict__ wqkv,
    unsigned short* __restrict__ wobf) {
  int i = blockIdx.x * blockDim.x + threadIdx.x;
  const float* src; unsigned short* dst; int off;
  if (i < 2097152)      { src = x;  dst = xbf;                  off = i; }
  else if (i < 3145728) { src = Wq; dst = wqkv;                 off = i - 2097152; }
  else if (i < 3407872) { src = Wk; dst = wqkv + 2048 * 2048;   off = i - 3145728; }
  else if (i < 3670016) { src = Wv; dst = wqkv + 2560 * 2048;   off = i - 3407872; }
  else                  { src = Wo; dst = wobf;                 off = i - 3670016; }
  float4 f = ((const float4*)src)[off];
  ushort4 o;
  o.x = f2bf(f.x); o.y = f2bf(f.y); o.z = f2bf(f.z); o.w = f2bf(f.w);
  ((ushort4*)dst)[off] = o;
}

// C = A @ B^T, 256x(BN) tile, BK=64, 8 waves (2 M x 4 N), 512 threads.
// 2 K-tiles per iteration, 8 phases; one half-tile stage per phase.
// Stage ledger (iter i handles tiles e=2i, o=2i+1):
//   S1=A1(o)->buf1  S2=A0(e+2)->buf0 S3=B0(e+2)->buf0 S4=B1(e+2)->buf0
//   S5=A1(e+2)->buf0 S6=A0(o+2)->buf1 S7=B0(o+2)->buf1 S8=B1(o+2)->buf1
// vmcnt(W) at phases 4 & 8 ONLY (W=6 for BN=256, 4 for BN=128): each wait
// lands exactly the 4 half-tiles the next tile needs, leaves 3 stages in
// flight; min issue->consume slack = 3 phases. Never vmcnt(0) in loop.
// Region safety: every region's overwrite is ISSUED >= 1 phase after its
// last read completed (reads complete within their phase via lgkmcnt(0)).
#define MMA_PHASE(MH, NHH, BF)                                                  \
  do {                                                                          \
    __builtin_amdgcn_s_setprio(1);                                              \
    _Pragma("unroll")                                                           \
    for (int kk = 0; kk < 2; ++kk)                                              \
      _Pragma("unroll")                                                         \
      for (int mr = 0; mr < 4; ++mr)                                            \
        _Pragma("unroll")                                                       \
        for (int nr = 0; nr < NR; ++nr)                                         \
          acc[(MH) * 4 + mr][(NHH) * NR + nr] =                                 \
              __builtin_amdgcn_mfma_f32_16x16x32_bf16(                          \
                  af[mr][kk], BF[nr][kk], acc[(MH) * 4 + mr][(NHH) * NR + nr],  \
                  0, 0, 0);                                                     \
    __builtin_amdgcn_s_setprio(0);                                              \
  } while (0)

#define WAITW()                                   \
  do {                                            \
    if constexpr (BN == 256) VMCNT(6);            \
    else                     VMCNT(4);            \
  } while (0)

template <int MODE, int BN, int NTN>
__global__ __launch_bounds__(512, 2) void gemm8p(
    const unsigned short* __restrict__ A,
    const unsigned short* __restrict__ Bm,
    int K,
    unsigned short* __restrict__ qbf,
    unsigned short* __restrict__ kbf,
    unsigned short* __restrict__ vtbf,
    float* __restrict__ kout,
    float* __restrict__ vout,
    float* __restrict__ cout) {
  constexpr int NR = BN / 128;        // B fragments per quadrant (2 or 1)
  constexpr int BHROW = BN / 2;       // rows per B half-tile
  __shared__ unsigned short As[2][256 * 64];
  __shared__ unsigned short Bs[2][BN * 64];

  const int tid  = threadIdx.x;
  const int lane = tid & 63;
  const int wave = tid >> 6;  // 0..7
  const int wm   = wave >> 2; // 0..1
  const int wn   = wave & 3;  // 0..3
  const int quad = lane >> 4;
  const int r16  = lane & 15;

  const int NT = K / 64;

  // XCD-aware chunked swizzle on linear block id (gridDim.x % 8 == 0).
  const int nwg = gridDim.x;
  const int id  = blockIdx.x;
  const int sid = (id & 7) * (nwg >> 3) + (id >> 3);
  const int by  = sid / NTN;
  const int bx  = sid % NTN;
  const int aRowBase = by * 256;
  const int bColBase = bx * BN;

  f32x4 zero = {0.f, 0.f, 0.f, 0.f};
  f32x4 acc[8][2 * NR];
#pragma unroll
  for (int i = 0; i < 8; ++i)
#pragma unroll
    for (int j = 0; j < 2 * NR; ++j) acc[i][j] = zero;

  // --- staging: one half-tile (128 rows A / BHROW rows B) per call.
  // LDS dest linear; global source pre-swizzled so LDS holds chunk
  // slot ^ (row&7) (T2 both-sides swizzle, rule #21).
  auto stageA = [&](int dbuf, int h, int t) {
    const int tt = t < NT ? t : NT - 1;
    const int k0 = tt * 64;
#pragma unroll
    for (int i = 0; i < 2; ++i) {
      const int chunk = (i * 8 + wave) * 64 + lane;  // 0..1023
      const int row = chunk >> 3;                    // 0..127
      const int slot = chunk & 7;
      const int gc = (slot ^ (row & 7)) * 8;
      gld_lds16(A + (size_t)(aRowBase + h * 128 + row) * K + k0 + gc,
                &As[dbuf][h * 8192 + (i * 8 + wave) * 512]);
    }
  };
  auto stageB = [&](int dbuf, int h, int t) {
    const int tt = t < NT ? t : NT - 1;
    const int k0 = tt * 64;
    if constexpr (BN == 256) {
#pragma unroll
      for (int i = 0; i < 2; ++i) {
        const int chunk = (i * 8 + wave) * 64 + lane;
        const int row = chunk >> 3;
        const int slot = chunk & 7;
        const int gc = (slot ^ (row & 7)) * 8;
        gld_lds16(Bm + (size_t)(bColBase + h * 128 + row) * K + k0 + gc,
                  &Bs[dbuf][h * 8192 + (i * 8 + wave) * 512]);
      }
    } else {
      const int chunk = wave * 64 + lane;  // 0..511
      const int row = chunk >> 3;          // 0..63
      const int slot = chunk & 7;
      const int gc = (slot ^ (row & 7)) * 8;
      gld_lds16(Bm + (size_t)(bColBase + h * 64 + row) * K + k0 + gc,
                &Bs[dbuf][h * 4096 + wave * 512]);
    }
  };

  bf16x8 af[4][2];      // current A half fragments
  bf16x8 b0[NR][2];     // B half-0 fragments
  bf16x8 b1[NR][2];     // B half-1 fragments

  auto readA = [&](int sbuf, int mh) {
#pragma unroll
    for (int mr = 0; mr < 4; ++mr)
#pragma unroll
      for (int kk = 0; kk < 2; ++kk) {
        const int row = mh * 128 + wm * 64 + mr * 16 + r16;
        const int slot = (kk * 4 + quad) ^ (r16 & 7);
        af[mr][kk] = ds_read128(&As[sbuf][row * 64 + slot * 8]);
      }
  };
  auto readB = [&](int sbuf, int nh, bf16x8 (&bf)[NR][2]) {
#pragma unroll
    for (int nr = 0; nr < NR; ++nr)
#pragma unroll
      for (int kk = 0; kk < 2; ++kk) {
        const int row = nh * BHROW + wn * (BN / 8) + nr * 16 + r16;
        const int slot = (kk * 4 + quad) ^ (r16 & 7);
        bf[nr][kk] = ds_read128(&Bs[sbuf][row * 64 + slot * 8]);
      }
  };

  // --- prologue: tile0 full + tile1 {A0,B0,B1}; wait leaves last 3 stages.
  stageA(0, 0, 0);   // A0(0)
  stageB(0, 0, 0);   // B0(0)
  stageB(0, 1, 0);   // B1(0)
  stageA(0, 1, 0);   // A1(0)
  stageA(1, 0, 1);   // A0(1)
  stageB(1, 0, 1);   // B0(1)
  stageB(1, 1, 1);   // B1(1)
  WAITW();
  BAR(); SB();

  const int NIT = NT / 2;
  for (int i = 0; i < NIT; ++i) {
    const int e2 = 2 * i + 2, o2 = 2 * i + 3;

    // Ph1 (tile e, q00): read A0,B0 buf0; S1 = A1(o)->buf1.
    readA(0, 0); readB(0, 0, b0);
    stageA(1, 1, 2 * i + 1);
    BAR();
    LGKM0();
    MMA_PHASE(0, 0, b0);
    BAR(); SB();

    // Ph2 (e, q01): read B1 buf0; S2 = A0(e+2)->buf0.
    readB(0, 1, b1);
    stageA(0, 0, e2);
    BAR();
    LGKM0();
    MMA_PHASE(0, 1, b1);
    BAR(); SB();

    // Ph3 (e, q10): read A1 buf0; S3 = B0(e+2)->buf0.
    readA(0, 1);
    stageB(0, 0, e2);
    BAR();
    LGKM0();
    MMA_PHASE(1, 0, b0);
    BAR(); SB();

    // Ph4 (e, q11): no reads; S4 = B1(e+2)->buf0; counted wait.
    stageB(0, 1, e2);
    BAR();
    MMA_PHASE(1, 1, b1);
    WAITW();
    BAR(); SB();

    // Ph5 (tile o, q00): read A0,B0 buf1; S5 = A1(e+2)->buf0.
    readA(1, 0); readB(1, 0, b0);
    stageA(0, 1, e2);
    BAR();
    LGKM0();
    MMA_PHASE(0, 0, b0);
    BAR(); SB();

    // Ph6 (o, q01): read B1 buf1; S6 = A0(o+2)->buf1.
    readB(1, 1, b1);
    stageA(1, 0, o2);
    BAR();
    LGKM0();
    MMA_PHASE(0, 1, b1);
    BAR(); SB();

    // Ph7 (o, q10): read A1 buf1; S7 = B0(o+2)->buf1.
    readA(1, 1);
    stageB(1, 0, o2);
    BAR();
    LGKM0();
    MMA_PHASE(1, 0, b0);
    BAR(); SB();

    // Ph8 (o, q11): no reads; S8 = B1(o+2)->buf1; counted wait.
    stageB(1, 1, o2);
    BAR();
    MMA_PHASE(1, 1, b1);
    WAITW();
    BAR(); SB();
  }
  VMCNT(0);  // hygiene before exit

  // --- epilogue: C write.
#pragma unroll
  for (int mi = 0; mi < 8; ++mi) {
    const int mh = mi >> 2, mr = mi & 3;
#pragma unroll
    for (int ni = 0; ni < 2 * NR; ++ni) {
      const int nh = ni / NR, nr = ni % NR;
      const int rowb = aRowBase + mh * 128 + wm * 64 + mr * 16 + quad * 4;
      const int col  = bColBase +
                       (BN == 256 ? nh * 128 + wn * 32 + nr * 16
                                  : nh * 64 + wn * 16) + r16;
#pragma unroll
      for (int reg = 0; reg < 4; ++reg) {
        const float v = acc[mi][ni][reg];
        const int m = rowb + reg;
        if (MODE == 1) {
          cout[(size_t)m * DOUT + col] = v;
        } else {
          if (col < 2048) {
            qbf[(size_t)m * DOUT + col] = f2bf(v * QSCALE);
          } else if (col < 2560) {
            const int gg = (col - 2048) >> 6, d = col & 63;
            const int b = m >> 11, s = m & 2047;
            const size_t idx = ((size_t)(b * NKV + gg) * S_ + s) * HD + d;
            kbf[idx]  = f2bf(v);
            kout[idx] = v;
          } else {
            const int gg = (col - 2560) >> 6, d = col & 63;
            const int b = m >> 11, s = m & 2047;
            vtbf[((size_t)(b * NKV + gg) * HD + d) * S_ + s]  = f2bf(v);
            vout[((size_t)(b * NKV + gg) * S_ + s) * HD + d] = v;
          }
        }
      }
    }
  }
}

// Flash attention, causal, m=0 softmax, in-register P (S^T operand-swap).
// 8 waves: group 0 (waves 0-3) = heavy tile (63-pairI), group 1 = light tile
// (pairI); wave = one head. K/V double-buffered via global_load_lds with
// prefetch-before-compute.
__global__ __launch_bounds__(512, 4) void attn_kernel(
    const unsigned short* __restrict__ Q,   // [B*S][DOUT] bf16 (scaled)
    const unsigned short* __restrict__ Kb,  // [B*NKV][S][HD] bf16
    const unsigned short* __restrict__ VT,  // [B*NKV][HD][S] bf16
    unsigned short* __restrict__ ctx) {     // [B*S][DOUT] bf16
  __shared__ unsigned short Kbuf[2][4096];  // 64 keys x 64 d, XOR-swizzled
  __shared__ unsigned short Vbuf[2][4096];  // 64 d x 64 keys, XOR-swizzled

  const int tid  = threadIdx.x;
  const int lane = tid & 63;
  const int wave = tid >> 6;   // 0..7
  const int grp  = wave >> 2;  // 0 = heavy tile, 1 = light tile
  const int hw   = wave & 3;
  const int quad = lane >> 4;
  const int r16  = lane & 15;
  const int g    = blockIdx.y;
  const int b    = blockIdx.z;
  const int h    = g * 4 + hw;
  const int pairI = blockIdx.x;  // 0..31, heavy-first
  const int q0     = grp ? pairI * 32 : (63 - pairI) * 32;
  const int nT_own = grp ? pairI / 2 + 1 : (63 - pairI) / 2 + 1;
  const int nTa    = (63 - pairI) / 2 + 1;  // block loop bound

  const unsigned short* Kh  = Kb + (size_t)(b * NKV + g) * S_ * HD;
  const unsigned short* VTh = VT + (size_t)(b * NKV + g) * HD * S_;

  const int srow   = lane >> 3;
  const int schunk = (lane & 7) ^ srow;

  // Q fragments (B-operand of S^T MFMA; same layout as A-operand)
  bf16x8 aq[2][2];
#pragma unroll
  for (int mt = 0; mt < 2; ++mt)
#pragma unroll
    for (int kk = 0; kk < 2; ++kk)
      aq[mt][kk] = *(const bf16x8*)(Q + (size_t)(b * S_ + q0 + mt * 16 + r16) * DOUT +
                                    h * HD + kk * 32 + quad * 8);

  bf16x4 ones4;
#pragma unroll
  for (int i = 0; i < 4; ++i) ones4[i] = (short)0x3F80;

  f32x4 zero = {0.f, 0.f, 0.f, 0.f};
  f32x4 o[2][4];  // [mt][dt]; C layout: row=q=quad*4+r, col=d=dt*16+r16
  f32x4 l[2];
#pragma unroll
  for (int mt = 0; mt < 2; ++mt) {
    l[mt] = zero;
#pragma unroll
    for (int dt = 0; dt < 4; ++dt) o[mt][dt] = zero;
  }

  // each wave stages one 8-row segment of K and of V^T (wave-uniform base)
  auto stage = [&](int buf, int kt) {
    const int kbase = kt * 64;
    gld_lds16(Kh + (size_t)(kbase + wave * 8 + srow) * HD + schunk * 8,
              &Kbuf[buf][wave * 512]);
    gld_lds16(VTh + (size_t)(wave * 8 + srow) * S_ + kbase + schunk * 8,
              &Vbuf[buf][wave * 512]);
  };

  stage(0, 0);
  __syncthreads();

  for (int kt = 0; kt < nTa; ++kt) {
    const int buf = kt & 1;
    if (kt + 1 < nTa) stage(buf ^ 1, kt + 1);

    if (kt < nT_own) {
      // K fragments: A-operand of S^T MFMA (m=key=r16 within tile nt)
      bf16x8 bk[4][2];
#pragma unroll
      for (int nt = 0; nt < 4; ++nt)
#pragma unroll
        for (int kk = 0; kk < 2; ++kk) {
          const int seg = nt * 2 + (r16 >> 3), r = r16 & 7;
          const int slot = (kk * 4 + quad) ^ r;
          bk[nt][kk] = *(const bf16x8*)&Kbuf[buf][seg * 512 + r * 64 + slot * 8];
        }

      const bool last = (kt == nT_own - 1);
#pragma unroll
      for (int mt = 0; mt < 2; ++mt) {
        // S^T = K.Q^T
        f32x4 st[4];
#pragma unroll
        for (int nt = 0; nt < 4; ++nt) st[nt] = zero;
#pragma unroll
        for (int kk = 0; kk < 2; ++kk)
#pragma unroll
          for (int nt = 0; nt < 4; ++nt)
            st[nt] = __builtin_amdgcn_mfma_f32_16x16x32_bf16(bk[nt][kk], aq[mt][kk], st[nt], 0, 0, 0);

        // mask + exp2 -> P A-fragments (K=16 layout), truncating bf16 pack
        bf16x4 pf[4];
#pragma unroll
        for (int nt = 0; nt < 4; ++nt) {
#pragma unroll
          for (int r = 0; r < 4; ++r) {
            float s = st[nt][r];
            if (last) {
              const int key = kt * 64 + nt * 16 + quad * 4 + r;
              const int row = q0 + mt * 16 + r16;
              if (key > row) s = -1e38f;
            }
            const float p = __builtin_amdgcn_exp2f(s);
            pf[nt][r] = (short)(__float_as_uint(p) >> 16);
          }
        }
        // row-sums via ones-MFMA, then PV with just-in-time V fragments
#pragma unroll
        for (int nt = 0; nt < 4; ++nt) l[mt] = mfma16(pf[nt], ones4, l[mt]);
#pragma unroll
        for (int dt = 0; dt < 4; ++dt) {
          const int seg = dt * 2 + (r16 >> 3), r = r16 & 7;
#pragma unroll
          for (int nt = 0; nt < 4; ++nt) {
            const int slot = (nt * 2 + (quad >> 1)) ^ r;
            bf16x4 bv = *(const bf16x4*)&Vbuf[buf][seg * 512 + r * 64 + slot * 8 + (quad & 1) * 4];
            o[mt][dt] = mfma16(pf[nt], bv, o[mt][dt]);
          }
        }
      }
    }

    __syncthreads();  // prefetch aged a full compute phase; swap buffers
  }

#pragma unroll
  for (int mt = 0; mt < 2; ++mt) {
    f32x4 rl;
#pragma unroll
    for (int r = 0; r < 4; ++r) rl[r] = __builtin_amdgcn_rcpf(l[mt][r]);
#pragma unroll
    for (int dt = 0; dt < 4; ++dt)
#pragma unroll
      for (int r = 0; r < 4; ++r) {
        const int qq = q0 + mt * 16 + quad * 4 + r;
        ctx[(size_t)(b * S_ + qq) * DOUT + h * HD + dt * 16 + r16] =
            f2bf(o[mt][dt][r] * rl[r]);
      }
  }
}

extern "C" void kernel_launch(void* const* d_in, const int* in_sizes, int n_in,
                              void* d_out, int out_size, void* d_ws, size_t ws_size,
                              hipStream_t stream) {
  const float* x  = (const float*)d_in[0];
  const float* Wq = (const float*)d_in[1];
  const float* Wk = (const float*)d_in[2];
  const float* Wv = (const float*)d_in[3];
  const float* Wo = (const float*)d_in[4];

  float* out  = (float*)d_out;
  float* keys = out + (size_t)B_ * S_ * DOUT;
  float* vals = keys + (size_t)B_ * NKV * S_ * HD;

  unsigned short* xbf  = (unsigned short*)d_ws;
  unsigned short* wqkv = xbf  + (size_t)B_ * S_ * DIN;
  unsigned short* wobf = wqkv + (size_t)NQKV * DIN;
  unsigned short* qbf  = wobf + (size_t)DIN * DOUT;
  unsigned short* kbf  = qbf  + (size_t)B_ * S_ * DOUT;
  unsigned short* vtbf = kbf  + (size_t)B_ * NKV * S_ * HD;
  unsigned short* ctx  = vtbf + (size_t)B_ * NKV * S_ * HD;

  cvt_all<<<dim3(4718592 / 256), dim3(256), 0, stream>>>(x, Wq, Wk, Wv, Wo,
                                                         xbf, wqkv, wobf);

  // QKV: M=4096, N=3072, 256x256 tiles -> 16x12 = 192 blocks (one round).
  gemm8p<0, 256, 12><<<dim3(192), dim3(512), 0, stream>>>(
      xbf, wqkv, DIN, qbf, kbf, vtbf, keys, vals, nullptr);

  attn_kernel<<<dim3(32, NKV, B_), dim3(512), 0, stream>>>(qbf, kbf, vtbf, ctx);

  // Wo: M=4096, N=2048, 256x128 tiles -> 16x16 = 256 blocks (100% coverage).
  gemm8p<1, 128, 16><<<dim3(256), dim3(512), 0, stream>>>(
      ctx, wobf, DOUT, nullptr, nullptr, nullptr, nullptr, nullptr, out);
}

// Round 7
// 286.804 us; speedup vs baseline: 1.1462x; 1.0308x over previous
//
#include <hip/hip_runtime.h>

// GQA fused pipeline, bf16 MFMA, gfx950.
// cvt(fp32->bf16) -> fused QKV GEMM (2-K-tile/8-phase, waits at Ph3/Ph7,
// publish-barrier-correct pipelined asm ds_reads, T2 swizzle + T5 setprio)
// -> flash attention (unchanged) -> Wo GEMM (same schedule, 256x128 tile).
//
// PUBLISH RULE (R6 lesson): vmcnt is PER-WAVE; half-tiles are staged
// cooperatively. A ds_read of a staged region is legal only after a barrier
// that follows every wave's counted vmcnt-wait landing that region.

#define B_   2
#define S_   2048
#define DIN  2048
#define NH   32
#define NKV  8
#define HD   64
#define DOUT 2048
#define NQKV 3072

#define QSCALE 0.18033688f  // 0.125 * log2(e), folded into Q

typedef short bf16x8 __attribute__((ext_vector_type(8)));
typedef short bf16x4 __attribute__((ext_vector_type(4)));
typedef float f32x4  __attribute__((ext_vector_type(4)));

__device__ __forceinline__ unsigned short f2bf(float f) {
  unsigned int u = __float_as_uint(f);
  u += 0x7fff + ((u >> 16) & 1);  // RNE
  return (unsigned short)(u >> 16);
}

__device__ __forceinline__ f32x4 mfma16(bf16x4 a, bf16x4 b, f32x4 c) {
#if __has_builtin(__builtin_amdgcn_mfma_f32_16x16x16bf16_1k)
  return __builtin_amdgcn_mfma_f32_16x16x16bf16_1k(a, b, c, 0, 0, 0);
#else
  asm volatile("v_mfma_f32_16x16x16_bf16 %0, %1, %2, %0" : "+v"(c) : "v"(a), "v"(b));
  return c;
#endif
}

__device__ __forceinline__ void gld_lds16(const void* gptr, void* lptr) {
  __builtin_amdgcn_global_load_lds(
      (const __attribute__((address_space(1))) unsigned int*)gptr,
      (__attribute__((address_space(3))) unsigned int*)lptr,
      16, 0, 0);
}

// Inline-asm LDS read: invisible to the backend's aliasing analysis (no
// compiler-inserted vmcnt(0) against outstanding global_load_lds). Ordering
// is the ledger's job. Consumption needs lgkmcnt(0)+sched_barrier(0).
__device__ __forceinline__ bf16x8 ds_read128(const unsigned short* p) {
  bf16x8 r;
  asm volatile("ds_read_b128 %0, %1"
               : "=v"(r)
               : "v"((const __attribute__((address_space(3))) unsigned short*)p));
  return r;
}

#define BAR() __builtin_amdgcn_s_barrier()
#define SB()  __builtin_amdgcn_sched_barrier(0)
#define VMCNT(n) asm volatile("s_waitcnt vmcnt(" #n ")")
#define LGKM0()                                   \
  do {                                            \
    asm volatile("s_waitcnt lgkmcnt(0)");         \
    __builtin_amdgcn_sched_barrier(0);            \
  } while (0)

// single conversion kernel for all 5 tensors (boundaries multiples of 256).
__global__ __launch_bounds__(256) void cvt_all(
    const float* __restrict__ x,  const float* __restrict__ Wq,
    const float* __restrict__ Wk, const float* __restrict__ Wv,
    const float* __restrict__ Wo,
    unsigned short* __restrict__ xbf, unsigned short* __restrict__ wqkv,
    unsigned short* __restrict__ wobf) {
  int i = blockIdx.x * blockDim.x + threadIdx.x;
  const float* src; unsigned short* dst; int off;
  if (i < 2097152)      { src = x;  dst = xbf;                  off = i; }
  else if (i < 3145728) { src = Wq; dst = wqkv;                 off = i - 2097152; }
  else if (i < 3407872) { src = Wk; dst = wqkv + 2048 * 2048;   off = i - 3145728; }
  else if (i < 3670016) { src = Wv; dst = wqkv + 2560 * 2048;   off = i - 3407872; }
  else                  { src = Wo; dst = wobf;                 off = i - 3670016; }
  float4 f = ((const float4*)src)[off];
  ushort4 o;
  o.x = f2bf(f.x); o.y = f2bf(f.y); o.z = f2bf(f.z); o.w = f2bf(f.w);
  ((ushort4*)dst)[off] = o;
}

// C = A @ B^T, 256x(BN) tile, BK=64, 8 waves (2M x 4N), 512 threads.
// 2 K-tiles/iter, 8 phases, one half-tile stage per phase.
// Stage ledger (iter i, e=2i buf0, o=2i+1 buf1):
//   S1=A1(o)b1  S2=A0(e+2)b0 S3=B0(e+2)b0 S4=B1(e+2)b0
//   S5=A1(e+2)b0 S6=A0(o+2)b1 S7=B0(o+2)b1 S8=B1(o+2)b1
// Counted waits at END of Ph3 (W1) and Ph7 (W2): vmcnt(4) BN=256 /
// vmcnt(3) BN=128. W1 completes {prevS6,prevS7,prevS8,S1} = tile o;
// W2 completes {S2..S5} = tile e+2. Publish barriers = Ph3/Ph7 ending BARs.
// Reads: Ph4/Ph8 issue next tile's A0/B0 (after publish BAR, before MFMA ->
// drain overlaps MFMA); Ph1/Ph5 hoist B1, Ph2/Ph6 hoist A1 (data published
// >=1 barrier earlier). Every read retires at the NEXT phase's lgkmcnt(0).
// All 8 region WARs: overwrite issues >=1 barrier after last read retired.
#define MMA_PHASE(MH, NHH, AF, BF)                                              \
  do {                                                                          \
    __builtin_amdgcn_s_setprio(1);                                              \
    _Pragma("unroll")                                                           \
    for (int kk = 0; kk < 2; ++kk)                                              \
      _Pragma("unroll")                                                         \
      for (int mr = 0; mr < 4; ++mr)                                            \
        _Pragma("unroll")                                                       \
        for (int nr = 0; nr < NR; ++nr)                                         \
          acc[(MH) * 4 + mr][(NHH) * NR + nr] =                                 \
              __builtin_amdgcn_mfma_f32_16x16x32_bf16(                          \
                  AF[mr][kk], BF[nr][kk], acc[(MH) * 4 + mr][(NHH) * NR + nr],  \
                  0, 0, 0);                                                     \
    __builtin_amdgcn_s_setprio(0);                                              \
  } while (0)

#define WAITW()                                   \
  do {                                            \
    if constexpr (BN == 256) VMCNT(4);            \
    else                     VMCNT(3);            \
  } while (0)

template <int MODE, int BN, int NTN>
__global__ __launch_bounds__(512, 2) void gemm8p(
    const unsigned short* __restrict__ A,
    const unsigned short* __restrict__ Bm,
    int K,
    unsigned short* __restrict__ qbf,
    unsigned short* __restrict__ kbf,
    unsigned short* __restrict__ vtbf,
    float* __restrict__ kout,
    float* __restrict__ vout,
    float* __restrict__ cout) {
  constexpr int NR = BN / 128;        // B fragments per quadrant (2 or 1)
  constexpr int BHROW = BN / 2;       // rows per B half-tile
  __shared__ unsigned short As[2][256 * 64];
  __shared__ unsigned short Bs[2][BN * 64];

  const int tid  = threadIdx.x;
  const int lane = tid & 63;
  const int wave = tid >> 6;  // 0..7
  const int wm   = wave >> 2; // 0..1
  const int wn   = wave & 3;  // 0..3
  const int quad = lane >> 4;
  const int r16  = lane & 15;

  const int NT = K / 64;

  // XCD-aware chunked swizzle on linear block id (gridDim.x % 8 == 0).
  const int nwg = gridDim.x;
  const int id  = blockIdx.x;
  const int sid = (id & 7) * (nwg >> 3) + (id >> 3);
  const int by  = sid / NTN;
  const int bx  = sid % NTN;
  const int aRowBase = by * 256;
  const int bColBase = bx * BN;

  f32x4 zero = {0.f, 0.f, 0.f, 0.f};
  f32x4 acc[8][2 * NR];
#pragma unroll
  for (int i = 0; i < 8; ++i)
#pragma unroll
    for (int j = 0; j < 2 * NR; ++j) acc[i][j] = zero;

  // --- staging: one half-tile per call; LDS dest linear; global source
  // pre-swizzled so LDS holds chunk slot ^ (row&7) (T2 both-sides, rule #21).
  auto stageA = [&](int dbuf, int h, int t) {
    const int tt = t < NT ? t : NT - 1;
    const int k0 = tt * 64;
#pragma unroll
    for (int i = 0; i < 2; ++i) {
      const int chunk = (i * 8 + wave) * 64 + lane;  // 0..1023
      const int row = chunk >> 3;                    // 0..127
      const int slot = chunk & 7;
      const int gc = (slot ^ (row & 7)) * 8;
      gld_lds16(A + (size_t)(aRowBase + h * 128 + row) * K + k0 + gc,
                &As[dbuf][h * 8192 + (i * 8 + wave) * 512]);
    }
  };
  auto stageB = [&](int dbuf, int h, int t) {
    const int tt = t < NT ? t : NT - 1;
    const int k0 = tt * 64;
    if constexpr (BN == 256) {
#pragma unroll
      for (int i = 0; i < 2; ++i) {
        const int chunk = (i * 8 + wave) * 64 + lane;
        const int row = chunk >> 3;
        const int slot = chunk & 7;
        const int gc = (slot ^ (row & 7)) * 8;
        gld_lds16(Bm + (size_t)(bColBase + h * 128 + row) * K + k0 + gc,
                  &Bs[dbuf][h * 8192 + (i * 8 + wave) * 512]);
      }
    } else {
      const int chunk = wave * 64 + lane;  // 0..511
      const int row = chunk >> 3;          // 0..63
      const int slot = chunk & 7;
      const int gc = (slot ^ (row & 7)) * 8;
      gld_lds16(Bm + (size_t)(bColBase + h * 64 + row) * K + k0 + gc,
                &Bs[dbuf][h * 4096 + wave * 512]);
    }
  };

  bf16x8 afA[4][2];     // A-half0 fragments
  bf16x8 afB[4][2];     // A-half1 fragments
  bf16x8 b0[NR][2];     // B-half0 fragments
  bf16x8 b1[NR][2];     // B-half1 fragments

  auto readA = [&](int sbuf, int mh, bf16x8 (&dst)[4][2]) {
#pragma unroll
    for (int mr = 0; mr < 4; ++mr)
#pragma unroll
      for (int kk = 0; kk < 2; ++kk) {
        const int row = mh * 128 + wm * 64 + mr * 16 + r16;
        const int slot = (kk * 4 + quad) ^ (r16 & 7);
        dst[mr][kk] = ds_read128(&As[sbuf][row * 64 + slot * 8]);
      }
  };
  auto readB = [&](int sbuf, int nh, bf16x8 (&dst)[NR][2]) {
#pragma unroll
    for (int nr = 0; nr < NR; ++nr)
#pragma unroll
      for (int kk = 0; kk < 2; ++kk) {
        const int row = nh * BHROW + wn * (BN / 8) + nr * 16 + r16;
        const int slot = (kk * 4 + quad) ^ (r16 & 7);
        dst[nr][kk] = ds_read128(&Bs[sbuf][row * 64 + slot * 8]);
      }
  };

  // --- prologue: mirrors steady state at Ph1 entry.
  stageA(0, 0, 0);   // A0(0)
  stageB(0, 0, 0);   // B0(0)
  stageB(0, 1, 0);   // B1(0)
  stageA(0, 1, 0);   // A1(0)
  stageA(1, 0, 1);   // A0(1)  (S6-equiv)
  stageB(1, 0, 1);   // B0(1)  (S7-equiv)
  WAITW();           // lands tile0; leaves {A0(1),B0(1)}
  BAR();             // PUBLISH tile0
  stageB(1, 1, 1);   // B1(1)  (S8-equiv)
  readA(0, 0, afA);  // A0(0) -- after publish BAR, retires at Ph1 LGKM0
  readB(0, 0, b0);   // B0(0)
  SB();

  const int NIT = NT / 2;
  for (int i = 0; i < NIT; ++i) {
    const int e2 = 2 * i + 2, o2 = 2 * i + 3;

    // Ph1 (e,q00): consume afA,b0; hoist B1(e)->b1 (published prev Ph7).
    stageA(1, 1, 2 * i + 1);              // S1
    BAR();
    LGKM0();
    readB(0, 1, b1); SB();
    MMA_PHASE(0, 0, afA, b0);
    BAR();

    // Ph2 (e,q01): consume afA,b1; hoist A1(e)->afB (published prev Ph7).
    stageA(0, 0, e2);                     // S2
    BAR();
    LGKM0();
    readA(0, 1, afB); SB();
    MMA_PHASE(0, 1, afA, b1);
    BAR();

    // Ph3 (e,q10): consume afB,b0; counted wait W1 lands tile o.
    stageB(0, 0, e2);                     // S3
    BAR();
    LGKM0();
    MMA_PHASE(1, 0, afB, b0);
    WAITW();                              // W1: {prevS6,prevS7,prevS8,S1}
    BAR();                                // PUBLISH tile o

    // Ph4 (e,q11): register-only MFMA; read A0(o),B0(o) overlapping MFMA.
    stageB(0, 1, e2);                     // S4
    BAR();
    readA(1, 0, afA);
    readB(1, 0, b0); SB();
    MMA_PHASE(1, 1, afB, b1);
    BAR();

    // Ph5 (o,q00): consume afA,b0; hoist B1(o)->b1 (published Ph3).
    stageA(0, 1, e2);                     // S5
    BAR();
    LGKM0();
    readB(1, 1, b1); SB();
    MMA_PHASE(0, 0, afA, b0);
    BAR();

    // Ph6 (o,q01): consume afA,b1; hoist A1(o)->afB (published Ph3).
    stageA(1, 0, o2);                     // S6
    BAR();
    LGKM0();
    readA(1, 1, afB); SB();
    MMA_PHASE(0, 1, afA, b1);
    BAR();

    // Ph7 (o,q10): consume afB,b0; counted wait W2 lands tile e+2.
    stageB(1, 0, o2);                     // S7
    BAR();
    LGKM0();
    MMA_PHASE(1, 0, afB, b0);
    WAITW();                              // W2: {S2,S3,S4,S5}
    BAR();                                // PUBLISH tile e+2

    // Ph8 (o,q11): register-only MFMA; read A0(e'),B0(e') overlapping MFMA.
    stageB(1, 1, o2);                     // S8
    BAR();
    readA(0, 0, afA);
    readB(0, 0, b0); SB();
    MMA_PHASE(1, 1, afB, b1);
    BAR();
  }
  asm volatile("s_waitcnt vmcnt(0) lgkmcnt(0)");  // drain before epilogue

  // --- epilogue: C write.
#pragma unroll
  for (int mi = 0; mi < 8; ++mi) {
    const int mh = mi >> 2, mr = mi & 3;
#pragma unroll
    for (int ni = 0; ni < 2 * NR; ++ni) {
      const int nh = ni / NR, nr = ni % NR;
      const int rowb = aRowBase + mh * 128 + wm * 64 + mr * 16 + quad * 4;
      const int col  = bColBase +
                       (BN == 256 ? nh * 128 + wn * 32 + nr * 16
                                  : nh * 64 + wn * 16) + r16;
#pragma unroll
      for (int reg = 0; reg < 4; ++reg) {
        const float v = acc[mi][ni][reg];
        const int m = rowb + reg;
        if (MODE == 1) {
          cout[(size_t)m * DOUT + col] = v;
        } else {
          if (col < 2048) {
            qbf[(size_t)m * DOUT + col] = f2bf(v * QSCALE);
          } else if (col < 2560) {
            const int gg = (col - 2048) >> 6, d = col & 63;
            const int b = m >> 11, s = m & 2047;
            const size_t idx = ((size_t)(b * NKV + gg) * S_ + s) * HD + d;
            kbf[idx]  = f2bf(v);
            kout[idx] = v;
          } else {
            const int gg = (col - 2560) >> 6, d = col & 63;
            const int b = m >> 11, s = m & 2047;
            vtbf[((size_t)(b * NKV + gg) * HD + d) * S_ + s]  = f2bf(v);
            vout[((size_t)(b * NKV + gg) * S_ + s) * HD + d] = v;
          }
        }
      }
    }
  }
}

// Flash attention, causal, m=0 softmax, in-register P (S^T operand-swap).
// 8 waves: group 0 (waves 0-3) = heavy tile (63-pairI), group 1 = light tile
// (pairI); wave = one head. K/V double-buffered via global_load_lds with
// prefetch-before-compute.
__global__ __launch_bounds__(512, 4) void attn_kernel(
    const unsigned short* __restrict__ Q,   // [B*S][DOUT] bf16 (scaled)
    const unsigned short* __restrict__ Kb,  // [B*NKV][S][HD] bf16
    const unsigned short* __restrict__ VT,  // [B*NKV][HD][S] bf16
    unsigned short* __restrict__ ctx) {     // [B*S][DOUT] bf16
  __shared__ unsigned short Kbuf[2][4096];  // 64 keys x 64 d, XOR-swizzled
  __shared__ unsigned short Vbuf[2][4096];  // 64 d x 64 keys, XOR-swizzled

  const int tid  = threadIdx.x;
  const int lane = tid & 63;
  const int wave = tid >> 6;   // 0..7
  const int grp  = wave >> 2;  // 0 = heavy tile, 1 = light tile
  const int hw   = wave & 3;
  const int quad = lane >> 4;
  const int r16  = lane & 15;
  const int g    = blockIdx.y;
  const int b    = blockIdx.z;
  const int h    = g * 4 + hw;
  const int pairI = blockIdx.x;  // 0..31, heavy-first
  const int q0     = grp ? pairI * 32 : (63 - pairI) * 32;
  const int nT_own = grp ? pairI / 2 + 1 : (63 - pairI) / 2 + 1;
  const int nTa    = (63 - pairI) / 2 + 1;  // block loop bound

  const unsigned short* Kh  = Kb + (size_t)(b * NKV + g) * S_ * HD;
  const unsigned short* VTh = VT + (size_t)(b * NKV + g) * HD * S_;

  const int srow   = lane >> 3;
  const int schunk = (lane & 7) ^ srow;

  // Q fragments (B-operand of S^T MFMA; same layout as A-operand)
  bf16x8 aq[2][2];
#pragma unroll
  for (int mt = 0; mt < 2; ++mt)
#pragma unroll
    for (int kk = 0; kk < 2; ++kk)
      aq[mt][kk] = *(const bf16x8*)(Q + (size_t)(b * S_ + q0 + mt * 16 + r16) * DOUT +
                                    h * HD + kk * 32 + quad * 8);

  bf16x4 ones4;
#pragma unroll
  for (int i = 0; i < 4; ++i) ones4[i] = (short)0x3F80;

  f32x4 zero = {0.f, 0.f, 0.f, 0.f};
  f32x4 o[2][4];  // [mt][dt]; C layout: row=q=quad*4+r, col=d=dt*16+r16
  f32x4 l[2];
#pragma unroll
  for (int mt = 0; mt < 2; ++mt) {
    l[mt] = zero;
#pragma unroll
    for (int dt = 0; dt < 4; ++dt) o[mt][dt] = zero;
  }

  // each wave stages one 8-row segment of K and of V^T (wave-uniform base)
  auto stage = [&](int buf, int kt) {
    const int kbase = kt * 64;
    gld_lds16(Kh + (size_t)(kbase + wave * 8 + srow) * HD + schunk * 8,
              &Kbuf[buf][wave * 512]);
    gld_lds16(VTh + (size_t)(wave * 8 + srow) * S_ + kbase + schunk * 8,
              &Vbuf[buf][wave * 512]);
  };

  stage(0, 0);
  __syncthreads();

  for (int kt = 0; kt < nTa; ++kt) {
    const int buf = kt & 1;
    if (kt + 1 < nTa) stage(buf ^ 1, kt + 1);

    if (kt < nT_own) {
      // K fragments: A-operand of S^T MFMA (m=key=r16 within tile nt)
      bf16x8 bk[4][2];
#pragma unroll
      for (int nt = 0; nt < 4; ++nt)
#pragma unroll
        for (int kk = 0; kk < 2; ++kk) {
          const int seg = nt * 2 + (r16 >> 3), r = r16 & 7;
          const int slot = (kk * 4 + quad) ^ r;
          bk[nt][kk] = *(const bf16x8*)&Kbuf[buf][seg * 512 + r * 64 + slot * 8];
        }

      const bool last = (kt == nT_own - 1);
#pragma unroll
      for (int mt = 0; mt < 2; ++mt) {
        // S^T = K.Q^T
        f32x4 st[4];
#pragma unroll
        for (int nt = 0; nt < 4; ++nt) st[nt] = zero;
#pragma unroll
        for (int kk = 0; kk < 2; ++kk)
#pragma unroll
          for (int nt = 0; nt < 4; ++nt)
            st[nt] = __builtin_amdgcn_mfma_f32_16x16x32_bf16(bk[nt][kk], aq[mt][kk], st[nt], 0, 0, 0);

        // mask + exp2 -> P A-fragments (K=16 layout), truncating bf16 pack
        bf16x4 pf[4];
#pragma unroll
        for (int nt = 0; nt < 4; ++nt) {
#pragma unroll
          for (int r = 0; r < 4; ++r) {
            float s = st[nt][r];
            if (last) {
              const int key = kt * 64 + nt * 16 + quad * 4 + r;
              const int row = q0 + mt * 16 + r16;
              if (key > row) s = -1e38f;
            }
            const float p = __builtin_amdgcn_exp2f(s);
            pf[nt][r] = (short)(__float_as_uint(p) >> 16);
          }
        }
        // row-sums via ones-MFMA, then PV with just-in-time V fragments
#pragma unroll
        for (int nt = 0; nt < 4; ++nt) l[mt] = mfma16(pf[nt], ones4, l[mt]);
#pragma unroll
        for (int dt = 0; dt < 4; ++dt) {
          const int seg = dt * 2 + (r16 >> 3), r = r16 & 7;
#pragma unroll
          for (int nt = 0; nt < 4; ++nt) {
            const int slot = (nt * 2 + (quad >> 1)) ^ r;
            bf16x4 bv = *(const bf16x4*)&Vbuf[buf][seg * 512 + r * 64 + slot * 8 + (quad & 1) * 4];
            o[mt][dt] = mfma16(pf[nt], bv, o[mt][dt]);
          }
        }
      }
    }

    __syncthreads();  // prefetch aged a full compute phase; swap buffers
  }

#pragma unroll
  for (int mt = 0; mt < 2; ++mt) {
    f32x4 rl;
#pragma unroll
    for (int r = 0; r < 4; ++r) rl[r] = __builtin_amdgcn_rcpf(l[mt][r]);
#pragma unroll
    for (int dt = 0; dt < 4; ++dt)
#pragma unroll
      for (int r = 0; r < 4; ++r) {
        const int qq = q0 + mt * 16 + quad * 4 + r;
        ctx[(size_t)(b * S_ + qq) * DOUT + h * HD + dt * 16 + r16] =
            f2bf(o[mt][dt][r] * rl[r]);
      }
  }
}

extern "C" void kernel_launch(void* const* d_in, const int* in_sizes, int n_in,
                              void* d_out, int out_size, void* d_ws, size_t ws_size,
                              hipStream_t stream) {
  const float* x  = (const float*)d_in[0];
  const float* Wq = (const float*)d_in[1];
  const float* Wk = (const float*)d_in[2];
  const float* Wv = (const float*)d_in[3];
  const float* Wo = (const float*)d_in[4];

  float* out  = (float*)d_out;
  float* keys = out + (size_t)B_ * S_ * DOUT;
  float* vals = keys + (size_t)B_ * NKV * S_ * HD;

  unsigned short* xbf  = (unsigned short*)d_ws;
  unsigned short* wqkv = xbf  + (size_t)B_ * S_ * DIN;
  unsigned short* wobf = wqkv + (size_t)NQKV * DIN;
  unsigned short* qbf  = wobf + (size_t)DIN * DOUT;
  unsigned short* kbf  = qbf  + (size_t)B_ * S_ * DOUT;
  unsigned short* vtbf = kbf  + (size_t)B_ * NKV * S_ * HD;
  unsigned short* ctx  = vtbf + (size_t)B_ * NKV * S_ * HD;

  cvt_all<<<dim3(4718592 / 256), dim3(256), 0, stream>>>(x, Wq, Wk, Wv, Wo,
                                                         xbf, wqkv, wobf);

  // QKV: M=4096, N=3072, 256x256 tiles -> 16x12 = 192 blocks (one round).
  gemm8p<0, 256, 12><<<dim3(192), dim3(512), 0, stream>>>(
      xbf, wqkv, DIN, qbf, kbf, vtbf, keys, vals, nullptr);

  attn_kernel<<<dim3(32, NKV, B_), dim3(512), 0, stream>>>(qbf, kbf, vtbf, ctx);

  // Wo: M=4096, N=2048, 256x128 tiles -> 16x16 = 256 blocks (100% coverage).
  gemm8p<1, 128, 16><<<dim3(256), dim3(512), 0, stream>>>(
      ctx, wobf, DOUT, nullptr, nullptr, nullptr, nullptr, nullptr, out);
}